// Round 10
// baseline (286.794 us; speedup 1.0000x reference)
//
#include <hip/hip_runtime.h>
#include <hip/hip_fp16.h>

#define N_NODES 50000
#define N_EDGES 600000
#define N_GRAPHS 64
#define IN_D 5
#define HID 128
#define EMB 64

#define CHUNK 512
#define NCHUNK ((N_NODES + CHUNK - 1) / CHUNK)   // 98
#define NREP 16          // psum replication factor (contention spread)
#define NLOC 4           // per-block local graph slots (16 sorted nodes span <=2)
#define TB 16            // nodes per tile (50000 = 3125*16, no tail)

typedef _Float16 half8 __attribute__((ext_vector_type(8)));
typedef float float4v __attribute__((ext_vector_type(4)));
typedef float floatx2 __attribute__((ext_vector_type(2)));

// e_pack entry: fp16(dinv[src]) in high 16 bits | src (fits 16 bits: 50000<65536)
__device__ __forceinline__ float ep_w(unsigned pe) {
    return (float)__ushort_as_half((unsigned short)(pe >> 16));
}
__device__ __forceinline__ unsigned ep_s(unsigned pe) { return pe & 0xffffu; }

// ---------- 1. init: zero cnt (must complete before k_count) ----------

__global__ __launch_bounds__(256) void k_init(int* __restrict__ cnt) {
    int tid = blockIdx.x * blockDim.x + threadIdx.x;
    if (tid < N_NODES) cnt[tid] = 0;
}

// ---------- 2. degree count + independent prep (xp pad, Wt transpose, psum zero) ----------

__global__ __launch_bounds__(256) void k_count(
        const int* __restrict__ dst, int* __restrict__ cnt,
        float* __restrict__ psum_rep,
        const float* __restrict__ W2, const float* __restrict__ W3,
        _Float16* __restrict__ Wt2, _Float16* __restrict__ Wt3,
        unsigned int* __restrict__ e_pack,
        const float* __restrict__ x, float* __restrict__ xp) {
    int tid = blockIdx.x * blockDim.x + threadIdx.x;
    int nt = gridDim.x * blockDim.x;
    if (tid < N_EDGES) atomicAdd(&cnt[dst[tid]], 1);
    if (tid < 8) e_pack[N_EDGES + tid] = 0u;  // safe pad for slot-reads (w=0)
    for (int i = tid; i < NREP * N_GRAPHS * HID; i += nt) psum_rep[i] = 0.f;
    for (int i = tid; i < N_NODES * 8; i += nt) {
        int f = i & 7, n = i >> 3;
        xp[i] = (f < IN_D) ? x[n * IN_D + f] : 0.f;
    }
    for (int i = tid; i < 2 * HID * HID; i += nt) {
        int rem = i & (HID * HID - 1);
        int k = rem & 127, f = rem >> 7;
        if (i < HID * HID) Wt2[rem] = (_Float16)W2[k * HID + f];
        else               Wt3[rem] = (_Float16)W3[k * HID + f];
    }
}

// ---------- 3. per-chunk sums + dinv ----------

__global__ void k_chunksum(const int* __restrict__ cnt, int* __restrict__ csum,
                           float* __restrict__ dinv) {
    __shared__ int sh[256];
    int b = blockIdx.x, t = threadIdx.x;
    int i0 = b * CHUNK + t, i1 = i0 + 256;
    int v = 0;
    if (i0 < N_NODES) { int c = cnt[i0]; v += c; dinv[i0] = rsqrtf((float)c + 1.0f); }
    if (i1 < N_NODES) { int c = cnt[i1]; v += c; dinv[i1] = rsqrtf((float)c + 1.0f); }
    sh[t] = v; __syncthreads();
    for (int off = 128; off > 0; off >>= 1) {
        if (t < off) sh[t] += sh[t + off];
        __syncthreads();
    }
    if (t == 0) csum[b] = sh[0];
}

// ---------- 4. per-chunk exclusive scan -> row_start ----------

__global__ void k_scan(const int* __restrict__ cnt, const int* __restrict__ csum,
                       int* __restrict__ row_start) {
    __shared__ int ws[4];
    int b = blockIdx.x, t = threadIdx.x;
    int lane = t & 63, w = t >> 6;

    int pre = 0;
    for (int j = lane; j < b; j += 64) pre += csum[j];
    #pragma unroll
    for (int off = 32; off > 0; off >>= 1) pre += __shfl_down(pre, off);
    pre = __shfl(pre, 0);

    int base = b * CHUNK;
    int i0 = base + 2 * t, i1 = i0 + 1;
    int c0 = (i0 < N_NODES) ? cnt[i0] : 0;
    int c1 = (i1 < N_NODES) ? cnt[i1] : 0;
    int v = c0 + c1;
    int s = v;
    #pragma unroll
    for (int off = 1; off < 64; off <<= 1) {
        int u = __shfl_up(s, off);
        if (lane >= off) s += u;
    }
    if (lane == 63) ws[w] = s;
    __syncthreads();
    if (t == 0) {
        int r = 0;
        #pragma unroll
        for (int j = 0; j < 4; ++j) { int xx = ws[j]; ws[j] = r; r += xx; }
    }
    __syncthreads();
    int excl = s - v + ws[w] + pre;
    if (i0 < N_NODES) row_start[i0] = excl;
    if (i1 < N_NODES) row_start[i1] = excl + c0;
    if (b == 0 && t == 0) row_start[N_NODES] = N_EDGES;
}

// ---------- 5. scatter edges into CSR order (4B packed records) ----------

__global__ __launch_bounds__(256) void k_scatter(
        const int* __restrict__ src, const int* __restrict__ dst,
        const float* __restrict__ dinv, const int* __restrict__ row_start,
        int* __restrict__ cnt, unsigned int* __restrict__ e_pack) {
    int e = blockIdx.x * blockDim.x + threadIdx.x;
    if (e >= N_EDGES) return;
    int d = dst[e];
    int pos = row_start[d] + atomicSub(&cnt[d], 1) - 1;
    int s = src[e];
    unsigned hw = (unsigned)__half_as_ushort(__float2half(dinv[s]));
    e_pack[pos] = (hw << 16) | (unsigned)s;
}

// ---------- 6. fused layer 1: paired slot-gather agg(xp) + gemm1 + bn + relu -> fp8 planes ----------
// lane = slot8*8 + q8. Two nodes' e_pack->gather chains kept in flight (R9 win, keep).
// Output H8 in PLANE layout: plane h (=features h*64..h*64+63) is a contiguous
// 3.2MB slab -> per-XCD-L2-resident when gathered by a phase-separated kernel.

__global__ __launch_bounds__(256) void k_agg1(
        const float* __restrict__ xp, const float* __restrict__ dinv,
        const int* __restrict__ row_start, const unsigned int* __restrict__ e_pack,
        const float* __restrict__ W1, const float* __restrict__ b1,
        const float* __restrict__ g1, const float* __restrict__ be1,
        unsigned short* __restrict__ H8u) {
    int t = threadIdx.x;
    int w = t >> 6, lane = t & 63;
    int slot8 = lane >> 3, q8 = lane & 7;
    int nb = blockIdx.x * TB;

    const float rs = rsqrtf(1.0f + 1e-5f);
    int fa = lane * 2, fb = fa + 1;
    float w1a[IN_D], w1b[IN_D];
    #pragma unroll
    for (int k = 0; k < IN_D; ++k) {
        w1a[k] = W1[k * HID + fa];
        w1b[k] = W1[k * HID + fb];
    }
    float b1a = b1[fa], b1b = b1[fb];
    float g1a = g1[fa] * rs, g1b = g1[fb] * rs;
    float e1a = be1[fa], e1b = be1[fb];
    size_t outbase = (size_t)(lane >> 5) * N_NODES * 32 + (lane & 31);

    #pragma unroll 1
    for (int i = 0; i < 2; ++i) {
        int n0 = nb + w * 4 + i * 2;
        int beg0 = row_start[n0], end0 = row_start[n0 + 1], end1 = row_start[n0 + 2];
        float acc0 = 0.f, acc1 = 0.f;
        int e0 = beg0, e1 = end0;
        while (e0 < end0 && e1 < end1) {
            unsigned pe0 = e_pack[e0 + slot8];
            unsigned pe1 = e_pack[e1 + slot8];
            float fw0 = (e0 + slot8 < end0) ? ep_w(pe0) : 0.f;
            float fw1 = (e1 + slot8 < end1) ? ep_w(pe1) : 0.f;
            float v0 = xp[(size_t)ep_s(pe0) * 8 + q8];
            float v1 = xp[(size_t)ep_s(pe1) * 8 + q8];
            acc0 = fmaf(fw0, v0, acc0);
            acc1 = fmaf(fw1, v1, acc1);
            e0 += 8; e1 += 8;
        }
        while (e0 < end0) {
            unsigned pe0 = e_pack[e0 + slot8];
            float fw0 = (e0 + slot8 < end0) ? ep_w(pe0) : 0.f;
            acc0 = fmaf(fw0, xp[(size_t)ep_s(pe0) * 8 + q8], acc0);
            e0 += 8;
        }
        while (e1 < end1) {
            unsigned pe1 = e_pack[e1 + slot8];
            float fw1 = (e1 + slot8 < end1) ? ep_w(pe1) : 0.f;
            acc1 = fmaf(fw1, xp[(size_t)ep_s(pe1) * 8 + q8], acc1);
            e1 += 8;
        }
        #pragma unroll
        for (int off = 8; off < 64; off <<= 1) {
            acc0 += __shfl_xor(acc0, off);
            acc1 += __shfl_xor(acc1, off);
        }
        #pragma unroll
        for (int p2 = 0; p2 < 2; ++p2) {
            int n = n0 + p2;
            float accs = p2 ? acc1 : acc0;
            float di = dinv[n];
            float av = di * fmaf(di, xp[(size_t)n * 8 + q8], accs);
            float a0 = __shfl(av, 0), a1 = __shfl(av, 1), a2 = __shfl(av, 2),
                  a3 = __shfl(av, 3), a4 = __shfl(av, 4);
            float va = b1a, vb = b1b;
            va = fmaf(a0, w1a[0], va); vb = fmaf(a0, w1b[0], vb);
            va = fmaf(a1, w1a[1], va); vb = fmaf(a1, w1b[1], vb);
            va = fmaf(a2, w1a[2], va); vb = fmaf(a2, w1b[2], vb);
            va = fmaf(a3, w1a[3], va); vb = fmaf(a3, w1b[3], vb);
            va = fmaf(a4, w1a[4], va); vb = fmaf(a4, w1b[4], vb);
            va = fmaf(va, g1a, e1a);
            vb = fmaf(vb, g1b, e1b);
            va = va > 0.f ? va : 0.f;
            vb = vb > 0.f ? vb : 0.f;
            int p = __builtin_amdgcn_cvt_pk_fp8_f32(va, vb, 0, false);
            H8u[outbase + (size_t)n * 32] = (unsigned short)(p & 0xffff);
        }
    }
}

// ---------- half-plane agg: one node's 64 features from one 3.2MB plane ----------
// lane = slot8*8 + q8: slot8 picks edge, q8 picks 8 features (uint2 = 8 fp8 = 1
// 64B line per edge). Result (dinv-scaled, fp16) stored to rowdst (global or LDS).

__device__ __forceinline__ void agg_half(
        const uint2* __restrict__ P, float di, int beg, int end,
        const unsigned int* __restrict__ e_pack,
        int n, int slot8, int q8, _Float16* __restrict__ rowdst) {
    float acc[8];
    #pragma unroll
    for (int j = 0; j < 8; ++j) acc[j] = 0.f;
    for (int e = beg; e < end; e += 8) {
        unsigned pe = e_pack[e + slot8];
        float fw = (e + slot8 < end) ? ep_w(pe) : 0.f;
        uint2 g = P[(size_t)ep_s(pe) * 8 + q8];
        floatx2 l0 = __builtin_amdgcn_cvt_pk_f32_fp8(g.x, false);
        floatx2 h0 = __builtin_amdgcn_cvt_pk_f32_fp8(g.x, true);
        floatx2 l1 = __builtin_amdgcn_cvt_pk_f32_fp8(g.y, false);
        floatx2 h1 = __builtin_amdgcn_cvt_pk_f32_fp8(g.y, true);
        acc[0] = fmaf(fw, l0[0], acc[0]);
        acc[1] = fmaf(fw, l0[1], acc[1]);
        acc[2] = fmaf(fw, h0[0], acc[2]);
        acc[3] = fmaf(fw, h0[1], acc[3]);
        acc[4] = fmaf(fw, l1[0], acc[4]);
        acc[5] = fmaf(fw, l1[1], acc[5]);
        acc[6] = fmaf(fw, h1[0], acc[6]);
        acc[7] = fmaf(fw, h1[1], acc[7]);
    }
    #pragma unroll
    for (int j = 0; j < 8; ++j) {
        float a = acc[j];
        a += __shfl_xor(a, 8); a += __shfl_xor(a, 16); a += __shfl_xor(a, 32);
        acc[j] = a;
    }
    if (slot8 == 0) {
        uint2 s = P[(size_t)n * 8 + q8];
        floatx2 l0 = __builtin_amdgcn_cvt_pk_f32_fp8(s.x, false);
        floatx2 h0 = __builtin_amdgcn_cvt_pk_f32_fp8(s.x, true);
        floatx2 l1 = __builtin_amdgcn_cvt_pk_f32_fp8(s.y, false);
        floatx2 h1 = __builtin_amdgcn_cvt_pk_f32_fp8(s.y, true);
        float sv[8] = {l0[0], l0[1], h0[0], h0[1], l1[0], l1[1], h1[0], h1[1]};
        half8 o;
        #pragma unroll
        for (int j = 0; j < 8; ++j)
            o[j] = (_Float16)(di * fmaf(di, sv[j], acc[j]));
        *(half8*)(rowdst + q8 * 8) = o;
    }
}

// ---------- 7a/8a. phase A: aggregate plane 0 for all nodes -> fp16 scratch ----------
// Whole-GPU works on ONE 3.2MB plane -> per-XCD L2-resident.

__global__ __launch_bounds__(256) void k_fuseA(
        const unsigned int* __restrict__ H8, const float* __restrict__ dinv,
        const int* __restrict__ row_start, const unsigned int* __restrict__ e_pack,
        _Float16* __restrict__ Ah) {
    int t = threadIdx.x;
    int w = t >> 6, lane = t & 63;
    int slot8 = lane >> 3, q8 = lane & 7;
    int nb = blockIdx.x * TB;
    const uint2* P = (const uint2*)H8;   // plane 0
    #pragma unroll 1
    for (int i = 0; i < 4; ++i) {
        int n = nb + w * 4 + i;
        agg_half(P, dinv[n], row_start[n], row_start[n + 1], e_pack,
                 n, slot8, q8, Ah + (size_t)n * 64);
    }
}

// ---------- 7b. phase B layer 2: plane-1 agg + scratch stage -> MFMA -> fp8 planes ----------

__global__ __launch_bounds__(256) void k_fuse2b(
        const unsigned int* __restrict__ H8, const _Float16* __restrict__ Ah,
        const float* __restrict__ dinv, const int* __restrict__ row_start,
        const unsigned int* __restrict__ e_pack, const _Float16* __restrict__ Wt,
        const float* __restrict__ bb, const float* __restrict__ gg,
        const float* __restrict__ bee, unsigned char* __restrict__ out8) {
    __shared__ __align__(16) _Float16 As[TB][136];
    int t = threadIdx.x;
    int w = t >> 6, lane = t & 63;
    int slot8 = lane >> 3, q8 = lane & 7;
    int nb = blockIdx.x * TB;

    // stage phase-A half (coalesced): 256 thr x uint2 covers 16 rows x 64 halfs
    {
        const uint2* srcp = (const uint2*)(Ah + (size_t)nb * 64);
        uint2 v = srcp[t];
        *(uint2*)&As[t >> 4][(t & 15) * 4] = v;
    }
    const uint2* P1 = (const uint2*)(H8 + (size_t)N_NODES * 16);  // plane 1
    #pragma unroll 1
    for (int i = 0; i < 4; ++i) {
        int n = nb + w * 4 + i;
        agg_half(P1, dinv[n], row_start[n], row_start[n + 1], e_pack,
                 n, slot8, q8, &As[w * 4 + i][64]);
    }
    __syncthreads();

    int quad = lane >> 4, r16 = lane & 15;
    half8 a[4];
    #pragma unroll
    for (int kb = 0; kb < 4; ++kb)
        a[kb] = *(const half8*)&As[r16][(kb * 4 + quad) * 8];
    const float rs = rsqrtf(1.0f + 1e-5f);
    #pragma unroll
    for (int fi = 0; fi < 2; ++fi) {
        int f = (w * 2 + fi) * 16 + r16;
        const half8* Brow = (const half8*)(Wt + (size_t)f * 128);
        float4v acc = {0.f, 0.f, 0.f, 0.f};
        #pragma unroll
        for (int kb = 0; kb < 4; ++kb)
            acc = __builtin_amdgcn_mfma_f32_16x16x32_f16(a[kb], Brow[kb * 4 + quad],
                                                         acc, 0, 0, 0);
        float b0 = bb[f], gf = gg[f] * rs, e0 = bee[f];
        size_t pbase = (size_t)(f >> 6) * N_NODES * 64 + (f & 63);
        #pragma unroll
        for (int rr = 0; rr < 4; ++rr) {
            float v = fmaf(acc[rr] + b0, gf, e0);
            v = v > 0.f ? v : 0.f;
            int p = __builtin_amdgcn_cvt_pk_fp8_f32(v, 0.f, 0, false);
            out8[pbase + (size_t)(nb + quad * 4 + rr) * 64] = (unsigned char)(p & 0xff);
        }
    }
}

// ---------- 8b. phase B layer 3: plane-1 agg + stage -> MFMA -> mean-pool ----------

__global__ __launch_bounds__(256) void k_fuse3b(
        const unsigned int* __restrict__ H8, const _Float16* __restrict__ Ah,
        const float* __restrict__ dinv, const int* __restrict__ row_start,
        const unsigned int* __restrict__ e_pack, const _Float16* __restrict__ Wt,
        const float* __restrict__ bb, const float* __restrict__ gg,
        const float* __restrict__ bee, const int* __restrict__ batch,
        float* __restrict__ psum_rep) {
    __shared__ __align__(16) _Float16 As[TB][136];
    __shared__ float sh_pool[NLOC][HID];
    int t = threadIdx.x;
    int w = t >> 6, lane = t & 63;
    int slot8 = lane >> 3, q8 = lane & 7;
    int blk = (int)blockIdx.x;
    int nb = blk * TB;

    for (int i = t; i < NLOC * HID; i += 256) ((float*)sh_pool)[i] = 0.f;
    {
        const uint2* srcp = (const uint2*)(Ah + (size_t)nb * 64);
        uint2 v = srcp[t];
        *(uint2*)&As[t >> 4][(t & 15) * 4] = v;
    }
    const uint2* P1 = (const uint2*)(H8 + (size_t)N_NODES * 16);  // plane 1
    #pragma unroll 1
    for (int i = 0; i < 4; ++i) {
        int n = nb + w * 4 + i;
        agg_half(P1, dinv[n], row_start[n], row_start[n + 1], e_pack,
                 n, slot8, q8, &As[w * 4 + i][64]);
    }

    int quad = lane >> 4, r16 = lane & 15;
    int g0 = batch[nb];
    int gi4[4];
    #pragma unroll
    for (int rr = 0; rr < 4; ++rr) gi4[rr] = batch[nb + quad * 4 + rr];
    __syncthreads();

    half8 a[4];
    #pragma unroll
    for (int kb = 0; kb < 4; ++kb)
        a[kb] = *(const half8*)&As[r16][(kb * 4 + quad) * 8];
    float* rep = psum_rep + (size_t)(blk & (NREP - 1)) * N_GRAPHS * HID;
    const float rs = rsqrtf(1.0f + 1e-5f);
    #pragma unroll
    for (int fi = 0; fi < 2; ++fi) {
        int f = (w * 2 + fi) * 16 + r16;
        const half8* Brow = (const half8*)(Wt + (size_t)f * 128);
        float4v acc = {0.f, 0.f, 0.f, 0.f};
        #pragma unroll
        for (int kb = 0; kb < 4; ++kb)
            acc = __builtin_amdgcn_mfma_f32_16x16x32_f16(a[kb], Brow[kb * 4 + quad],
                                                         acc, 0, 0, 0);
        float b0 = bb[f], gf = gg[f] * rs, e0 = bee[f];
        float partial = 0.f;
        int cur = -1;
        #pragma unroll
        for (int rr = 0; rr < 4; ++rr) {
            float v = fmaf(acc[rr] + b0, gf, e0);
            v = v > 0.f ? v : 0.f;
            int gi = gi4[rr];
            if (gi != cur) {
                if (cur >= 0) {
                    int idx = cur - g0;
                    if (idx < NLOC) atomicAdd(&sh_pool[idx][f], partial);
                    else            atomicAdd(&rep[cur * HID + f], partial);
                }
                partial = 0.f; cur = gi;
            }
            partial += v;
        }
        if (cur >= 0) {
            int idx = cur - g0;
            if (idx < NLOC) atomicAdd(&sh_pool[idx][f], partial);
            else            atomicAdd(&rep[cur * HID + f], partial);
        }
    }
    __syncthreads();
    // flush LDS partials: one replicated global atomic per (graph,f) present
    for (int i = t; i < NLOC * HID; i += 256) {
        int idx = i >> 7, ff = i & 127;
        float v = sh_pool[idx][ff];
        int g = g0 + idx;
        if (v != 0.f && g < N_GRAPHS) atomicAdd(&rep[g * HID + ff], v);
    }
}

// ---------- 9. projection (+ graph counts via binary search, no atomics) ----------

__device__ __forceinline__ int lower_bound_batch(const int* __restrict__ batch, int val) {
    int lo = 0, hi = N_NODES;
    while (lo < hi) {
        int mid = (lo + hi) >> 1;
        if (batch[mid] < val) lo = mid + 1;
        else hi = mid;
    }
    return lo;
}

__global__ void k_final(const float* __restrict__ psum_rep, const int* __restrict__ batch,
                        const float* __restrict__ Wp, const float* __restrict__ bp,
                        float* __restrict__ out) {
    __shared__ float s_p[HID];
    int gi = blockIdx.x, e = threadIdx.x;   // 64 threads
    for (int f = e; f < HID; f += EMB) {
        float v = 0.f;
        #pragma unroll
        for (int r = 0; r < NREP; ++r)
            v += psum_rep[(size_t)r * N_GRAPHS * HID + gi * HID + f];
        s_p[f] = v;
    }
    int lane = e & 63;
    int r = 0;
    if (lane < 2) r = lower_bound_batch(batch, gi + lane);
    int c0 = __shfl(r, 0), c1 = __shfl(r, 1);
    float inv = 1.0f / fmaxf((float)(c1 - c0), 1.0f);
    __syncthreads();
    float acc = bp[e];
    #pragma unroll 8
    for (int f = 0; f < HID; ++f)
        acc = fmaf(s_p[f] * inv, Wp[f * EMB + e], acc);
    out[gi * EMB + e] = acc;
}

// ---------- launcher ----------

extern "C" void kernel_launch(void* const* d_in, const int* in_sizes, int n_in,
                              void* d_out, int out_size, void* d_ws, size_t ws_size,
                              hipStream_t stream) {
    const float* x   = (const float*)d_in[0];
    const int*   src = (const int*)d_in[1];
    const int*   dst = (const int*)d_in[2];
    const int* batch = (const int*)d_in[3];
    const float* W1 = (const float*)d_in[4];
    const float* b1 = (const float*)d_in[5];
    const float* W2 = (const float*)d_in[6];
    const float* b2 = (const float*)d_in[7];
    const float* W3 = (const float*)d_in[8];
    const float* b3 = (const float*)d_in[9];
    const float* g1 = (const float*)d_in[10];
    const float* be1 = (const float*)d_in[11];
    const float* g2 = (const float*)d_in[12];
    const float* be2 = (const float*)d_in[13];
    const float* g3 = (const float*)d_in[14];
    const float* be3 = (const float*)d_in[15];
    const float* Wp = (const float*)d_in[16];
    const float* bp = (const float*)d_in[17];
    float* out = (float*)d_out;

    char* ws = (char*)d_ws;
    size_t o = 0;
    auto alloc = [&](size_t bytes) {
        void* pp = ws + o;
        o += bytes;
        o = (o + 255) & ~255ull;
        return pp;
    };
    int*      cnt       = (int*)alloc(N_NODES * 4);
    int*      row_start = (int*)alloc((N_NODES + 1) * 4);
    int*      csum      = (int*)alloc(NCHUNK * 4);
    float*    dinv      = (float*)alloc(N_NODES * 4);
    unsigned int* e_pack = (unsigned int*)alloc((size_t)(N_EDGES + 8) * 4);
    _Float16* Wt2       = (_Float16*)alloc(HID * HID * 2);
    _Float16* Wt3       = (_Float16*)alloc(HID * HID * 2);
    float*    xp        = (float*)alloc((size_t)N_NODES * 8 * 4);
    unsigned int* H8a   = (unsigned int*)alloc((size_t)N_NODES * HID);  // 2 fp8 planes
    unsigned int* H8b   = (unsigned int*)alloc((size_t)N_NODES * HID);
    _Float16* Ah        = (_Float16*)alloc((size_t)N_NODES * 64 * 2);   // phase-A scratch
    float*    psum_rep  = (float*)alloc((size_t)NREP * N_GRAPHS * HID * 4);

    k_init<<<(N_NODES + 255) / 256, 256, 0, stream>>>(cnt);
    k_count<<<(N_EDGES + 255) / 256, 256, 0, stream>>>(dst, cnt, psum_rep,
                                                       W2, W3, Wt2, Wt3, e_pack, x, xp);
    k_chunksum<<<NCHUNK, 256, 0, stream>>>(cnt, csum, dinv);
    k_scan<<<NCHUNK, 256, 0, stream>>>(cnt, csum, row_start);
    k_scatter<<<(N_EDGES + 255) / 256, 256, 0, stream>>>(src, dst, dinv, row_start,
                                                         cnt, e_pack);
    k_agg1<<<N_NODES / TB, 256, 0, stream>>>(xp, dinv, row_start, e_pack,
                                             W1, b1, g1, be1, (unsigned short*)H8a);
    k_fuseA<<<N_NODES / TB, 256, 0, stream>>>(H8a, dinv, row_start, e_pack, Ah);
    k_fuse2b<<<N_NODES / TB, 256, 0, stream>>>(H8a, Ah, dinv, row_start, e_pack, Wt2,
                                               b2, g2, be2, (unsigned char*)H8b);
    k_fuseA<<<N_NODES / TB, 256, 0, stream>>>(H8b, dinv, row_start, e_pack, Ah);
    k_fuse3b<<<N_NODES / TB, 256, 0, stream>>>(H8b, Ah, dinv, row_start, e_pack, Wt3,
                                               b3, g3, be3, batch, psum_rep);
    k_final<<<N_GRAPHS, EMB, 0, stream>>>(psum_rep, batch, Wp, bp, out);
}

// Round 11
// 263.591 us; speedup vs baseline: 1.0880x; 1.0880x over previous
//
#include <hip/hip_runtime.h>
#include <hip/hip_fp16.h>

#define N_NODES 50000
#define N_EDGES 600000
#define N_GRAPHS 64
#define IN_D 5
#define HID 128
#define EMB 64

#define CHUNK 512
#define NCHUNK ((N_NODES + CHUNK - 1) / CHUNK)   // 98
#define NREP 16          // psum replication factor (contention spread)
#define NLOC 4           // per-block local graph slots (16 sorted nodes span <=2)
#define TB 16            // nodes per fused agg+gemm tile (50000 = 3125*16, no tail)

typedef _Float16 half8 __attribute__((ext_vector_type(8)));
typedef float float4v __attribute__((ext_vector_type(4)));
typedef float floatx2 __attribute__((ext_vector_type(2)));

// e_pack entry: fp16(dinv[src]) in high 16 bits | src (fits 16 bits: 50000<65536)
__device__ __forceinline__ float ep_w(unsigned pe) {
    return (float)__ushort_as_half((unsigned short)(pe >> 16));
}
__device__ __forceinline__ unsigned ep_s(unsigned pe) { return pe & 0xffffu; }

// ---------- 1. init: zero cnt (must complete before k_count) ----------

__global__ __launch_bounds__(256) void k_init(int* __restrict__ cnt) {
    int tid = blockIdx.x * blockDim.x + threadIdx.x;
    if (tid < N_NODES) cnt[tid] = 0;
}

// ---------- 2. degree count + independent prep (xp pad, Wt transpose, psum zero) ----------

__global__ __launch_bounds__(256) void k_count(
        const int* __restrict__ dst, int* __restrict__ cnt,
        float* __restrict__ psum_rep,
        const float* __restrict__ W2, const float* __restrict__ W3,
        _Float16* __restrict__ Wt2, _Float16* __restrict__ Wt3,
        unsigned int* __restrict__ e_pack,
        const float* __restrict__ x, float* __restrict__ xp) {
    int tid = blockIdx.x * blockDim.x + threadIdx.x;
    int nt = gridDim.x * blockDim.x;
    if (tid < N_EDGES) atomicAdd(&cnt[dst[tid]], 1);
    if (tid < 8) e_pack[N_EDGES + tid] = 0u;  // safe pad for slot-reads (w=0)
    for (int i = tid; i < NREP * N_GRAPHS * HID; i += nt) psum_rep[i] = 0.f;
    for (int i = tid; i < N_NODES * 8; i += nt) {
        int f = i & 7, n = i >> 3;
        xp[i] = (f < IN_D) ? x[n * IN_D + f] : 0.f;
    }
    for (int i = tid; i < 2 * HID * HID; i += nt) {
        int rem = i & (HID * HID - 1);
        int k = rem & 127, f = rem >> 7;
        if (i < HID * HID) Wt2[rem] = (_Float16)W2[k * HID + f];
        else               Wt3[rem] = (_Float16)W3[k * HID + f];
    }
}

// ---------- 3. per-chunk sums + dinv ----------

__global__ void k_chunksum(const int* __restrict__ cnt, int* __restrict__ csum,
                           float* __restrict__ dinv) {
    __shared__ int sh[256];
    int b = blockIdx.x, t = threadIdx.x;
    int i0 = b * CHUNK + t, i1 = i0 + 256;
    int v = 0;
    if (i0 < N_NODES) { int c = cnt[i0]; v += c; dinv[i0] = rsqrtf((float)c + 1.0f); }
    if (i1 < N_NODES) { int c = cnt[i1]; v += c; dinv[i1] = rsqrtf((float)c + 1.0f); }
    sh[t] = v; __syncthreads();
    for (int off = 128; off > 0; off >>= 1) {
        if (t < off) sh[t] += sh[t + off];
        __syncthreads();
    }
    if (t == 0) csum[b] = sh[0];
}

// ---------- 4. per-chunk exclusive scan -> row_start ----------

__global__ void k_scan(const int* __restrict__ cnt, const int* __restrict__ csum,
                       int* __restrict__ row_start) {
    __shared__ int ws[4];
    int b = blockIdx.x, t = threadIdx.x;
    int lane = t & 63, w = t >> 6;

    int pre = 0;
    for (int j = lane; j < b; j += 64) pre += csum[j];
    #pragma unroll
    for (int off = 32; off > 0; off >>= 1) pre += __shfl_down(pre, off);
    pre = __shfl(pre, 0);

    int base = b * CHUNK;
    int i0 = base + 2 * t, i1 = i0 + 1;
    int c0 = (i0 < N_NODES) ? cnt[i0] : 0;
    int c1 = (i1 < N_NODES) ? cnt[i1] : 0;
    int v = c0 + c1;
    int s = v;
    #pragma unroll
    for (int off = 1; off < 64; off <<= 1) {
        int u = __shfl_up(s, off);
        if (lane >= off) s += u;
    }
    if (lane == 63) ws[w] = s;
    __syncthreads();
    if (t == 0) {
        int r = 0;
        #pragma unroll
        for (int j = 0; j < 4; ++j) { int xx = ws[j]; ws[j] = r; r += xx; }
    }
    __syncthreads();
    int excl = s - v + ws[w] + pre;
    if (i0 < N_NODES) row_start[i0] = excl;
    if (i1 < N_NODES) row_start[i1] = excl + c0;
    if (b == 0 && t == 0) row_start[N_NODES] = N_EDGES;
}

// ---------- 5. scatter edges into CSR order (4B packed records) ----------

__global__ __launch_bounds__(256) void k_scatter(
        const int* __restrict__ src, const int* __restrict__ dst,
        const float* __restrict__ dinv, const int* __restrict__ row_start,
        int* __restrict__ cnt, unsigned int* __restrict__ e_pack) {
    int e = blockIdx.x * blockDim.x + threadIdx.x;
    if (e >= N_EDGES) return;
    int d = dst[e];
    int pos = row_start[d] + atomicSub(&cnt[d], 1) - 1;
    int s = src[e];
    unsigned hw = (unsigned)__half_as_ushort(__float2half(dinv[s]));
    e_pack[pos] = (hw << 16) | (unsigned)s;
}

// ---------- 6. fused layer 1: paired slot-gather agg(xp) + gemm1 + bn + relu -> fp8 ----------
// lane = slot8*8 + q8. Two nodes' e_pack->gather chains kept in flight (R9 win).

__global__ __launch_bounds__(256) void k_agg1(
        const float* __restrict__ xp, const float* __restrict__ dinv,
        const int* __restrict__ row_start, const unsigned int* __restrict__ e_pack,
        const float* __restrict__ W1, const float* __restrict__ b1,
        const float* __restrict__ g1, const float* __restrict__ be1,
        unsigned short* __restrict__ H8u) {
    int t = threadIdx.x;
    int w = t >> 6, lane = t & 63;
    int slot8 = lane >> 3, q8 = lane & 7;
    int nb = blockIdx.x * TB;

    const float rs = rsqrtf(1.0f + 1e-5f);
    int fa = lane * 2, fb = fa + 1;
    float w1a[IN_D], w1b[IN_D];
    #pragma unroll
    for (int k = 0; k < IN_D; ++k) {
        w1a[k] = W1[k * HID + fa];
        w1b[k] = W1[k * HID + fb];
    }
    float b1a = b1[fa], b1b = b1[fb];
    float g1a = g1[fa] * rs, g1b = g1[fb] * rs;
    float e1a = be1[fa], e1b = be1[fb];

    #pragma unroll 1
    for (int i = 0; i < 2; ++i) {
        int n0 = nb + w * 4 + i * 2;
        int beg0 = row_start[n0], end0 = row_start[n0 + 1], end1 = row_start[n0 + 2];
        float acc0 = 0.f, acc1 = 0.f;
        int e0 = beg0, e1 = end0;
        while (e0 < end0 && e1 < end1) {
            unsigned pe0 = e_pack[e0 + slot8];
            unsigned pe1 = e_pack[e1 + slot8];
            float fw0 = (e0 + slot8 < end0) ? ep_w(pe0) : 0.f;
            float fw1 = (e1 + slot8 < end1) ? ep_w(pe1) : 0.f;
            float v0 = xp[(size_t)ep_s(pe0) * 8 + q8];
            float v1 = xp[(size_t)ep_s(pe1) * 8 + q8];
            acc0 = fmaf(fw0, v0, acc0);
            acc1 = fmaf(fw1, v1, acc1);
            e0 += 8; e1 += 8;
        }
        while (e0 < end0) {
            unsigned pe0 = e_pack[e0 + slot8];
            float fw0 = (e0 + slot8 < end0) ? ep_w(pe0) : 0.f;
            acc0 = fmaf(fw0, xp[(size_t)ep_s(pe0) * 8 + q8], acc0);
            e0 += 8;
        }
        while (e1 < end1) {
            unsigned pe1 = e_pack[e1 + slot8];
            float fw1 = (e1 + slot8 < end1) ? ep_w(pe1) : 0.f;
            acc1 = fmaf(fw1, xp[(size_t)ep_s(pe1) * 8 + q8], acc1);
            e1 += 8;
        }
        #pragma unroll
        for (int off = 8; off < 64; off <<= 1) {
            acc0 += __shfl_xor(acc0, off);
            acc1 += __shfl_xor(acc1, off);
        }
        #pragma unroll
        for (int p2 = 0; p2 < 2; ++p2) {
            int n = n0 + p2;
            float accs = p2 ? acc1 : acc0;
            float di = dinv[n];
            float av = di * fmaf(di, xp[(size_t)n * 8 + q8], accs);
            float a0 = __shfl(av, 0), a1 = __shfl(av, 1), a2 = __shfl(av, 2),
                  a3 = __shfl(av, 3), a4 = __shfl(av, 4);
            float va = b1a, vb = b1b;
            va = fmaf(a0, w1a[0], va); vb = fmaf(a0, w1b[0], vb);
            va = fmaf(a1, w1a[1], va); vb = fmaf(a1, w1b[1], vb);
            va = fmaf(a2, w1a[2], va); vb = fmaf(a2, w1b[2], vb);
            va = fmaf(a3, w1a[3], va); vb = fmaf(a3, w1b[3], vb);
            va = fmaf(a4, w1a[4], va); vb = fmaf(a4, w1b[4], vb);
            va = fmaf(va, g1a, e1a);
            vb = fmaf(vb, g1b, e1b);
            va = va > 0.f ? va : 0.f;
            vb = vb > 0.f ? vb : 0.f;
            int p = __builtin_amdgcn_cvt_pk_fp8_f32(va, vb, 0, false);
            H8u[(size_t)n * 64 + lane] = (unsigned short)(p & 0xffff);
        }
    }
}

// ---------- fp8 multi-edge agg (unpaired, R7 form): 1 gather inst = 8 edge-rows ----------

__device__ __forceinline__ void agg_node_fp8(
        const unsigned int* __restrict__ H8, const float* __restrict__ dinv,
        const int* __restrict__ row_start, const unsigned int* __restrict__ e_pack,
        int n, int slot8, int q8, _Float16* __restrict__ asrow) {
    float acc[16];
    #pragma unroll
    for (int j = 0; j < 16; ++j) acc[j] = 0.f;
    int beg = row_start[n], end = row_start[n + 1];
    for (int e = beg; e < end; e += 8) {
        unsigned pe = e_pack[e + slot8];
        float fw = (e + slot8 < end) ? ep_w(pe) : 0.f;
        uint4 g = ((const uint4*)(H8 + (size_t)ep_s(pe) * 32))[q8];
        unsigned int gw[4] = {g.x, g.y, g.z, g.w};
        #pragma unroll
        for (int q = 0; q < 4; ++q) {
            floatx2 lo = __builtin_amdgcn_cvt_pk_f32_fp8(gw[q], false);
            floatx2 hi = __builtin_amdgcn_cvt_pk_f32_fp8(gw[q], true);
            acc[4 * q + 0] = fmaf(fw, lo[0], acc[4 * q + 0]);
            acc[4 * q + 1] = fmaf(fw, lo[1], acc[4 * q + 1]);
            acc[4 * q + 2] = fmaf(fw, hi[0], acc[4 * q + 2]);
            acc[4 * q + 3] = fmaf(fw, hi[1], acc[4 * q + 3]);
        }
    }
    #pragma unroll
    for (int j = 0; j < 16; ++j) {
        float a = acc[j];
        a += __shfl_xor(a, 8);
        a += __shfl_xor(a, 16);
        a += __shfl_xor(a, 32);
        acc[j] = a;
    }
    if (slot8 == 0) {
        float di = dinv[n];
        uint4 s = ((const uint4*)(H8 + (size_t)n * 32))[q8];
        unsigned int sw[4] = {s.x, s.y, s.z, s.w};
        float sv[16];
        #pragma unroll
        for (int q = 0; q < 4; ++q) {
            floatx2 lo = __builtin_amdgcn_cvt_pk_f32_fp8(sw[q], false);
            floatx2 hi = __builtin_amdgcn_cvt_pk_f32_fp8(sw[q], true);
            sv[4 * q + 0] = lo[0]; sv[4 * q + 1] = lo[1];
            sv[4 * q + 2] = hi[0]; sv[4 * q + 3] = hi[1];
        }
        half8 o0, o1;
        #pragma unroll
        for (int j = 0; j < 8; ++j)
            o0[j] = (_Float16)(di * fmaf(di, sv[j], acc[j]));
        #pragma unroll
        for (int j = 0; j < 8; ++j)
            o1[j] = (_Float16)(di * fmaf(di, sv[j + 8], acc[j + 8]));
        *(half8*)(asrow + q8 * 16) = o0;
        *(half8*)(asrow + q8 * 16 + 8) = o1;
    }
}

// ---------- 7. fused layer 2: fp8 agg -> LDS(fp16) -> MFMA + bn + relu -> fp8 ----------

__global__ __launch_bounds__(256) void k_fuse2(
        const unsigned int* __restrict__ Hin, const float* __restrict__ dinv,
        const int* __restrict__ row_start, const unsigned int* __restrict__ e_pack,
        const _Float16* __restrict__ Wt,
        const float* __restrict__ bb, const float* __restrict__ gg,
        const float* __restrict__ bee, unsigned char* __restrict__ out8) {
    __shared__ __align__(16) _Float16 As[TB][136];
    int t = threadIdx.x;
    int w = t >> 6, lane = t & 63;
    int slot8 = lane >> 3, q8 = lane & 7;
    int nb = blockIdx.x * TB;

    #pragma unroll 1
    for (int i = 0; i < 4; ++i)
        agg_node_fp8(Hin, dinv, row_start, e_pack,
                     nb + w * 4 + i, slot8, q8, &As[w * 4 + i][0]);
    __syncthreads();

    int quad = lane >> 4, r16 = lane & 15;
    half8 a[4];
    #pragma unroll
    for (int kb = 0; kb < 4; ++kb)
        a[kb] = *(const half8*)&As[r16][(kb * 4 + quad) * 8];
    const float rs = rsqrtf(1.0f + 1e-5f);
    #pragma unroll
    for (int fi = 0; fi < 2; ++fi) {
        int f = (w * 2 + fi) * 16 + r16;
        const half8* Brow = (const half8*)(Wt + (size_t)f * 128);
        float4v acc = {0.f, 0.f, 0.f, 0.f};
        #pragma unroll
        for (int kb = 0; kb < 4; ++kb)
            acc = __builtin_amdgcn_mfma_f32_16x16x32_f16(a[kb], Brow[kb * 4 + quad],
                                                         acc, 0, 0, 0);
        float b0 = bb[f], gf = gg[f] * rs, e0 = bee[f];
        #pragma unroll
        for (int rr = 0; rr < 4; ++rr) {
            float v = fmaf(acc[rr] + b0, gf, e0);
            v = v > 0.f ? v : 0.f;
            int p = __builtin_amdgcn_cvt_pk_fp8_f32(v, 0.f, 0, false);
            out8[(size_t)(nb + quad * 4 + rr) * 128 + f] = (unsigned char)(p & 0xff);
        }
    }
}

// ---------- 8. fused layer 3: fp8 agg -> MFMA + bn + relu + mean-pool ----------

__global__ __launch_bounds__(256) void k_fuse3(
        const unsigned int* __restrict__ Hin, const float* __restrict__ dinv,
        const int* __restrict__ row_start, const unsigned int* __restrict__ e_pack,
        const _Float16* __restrict__ Wt,
        const float* __restrict__ bb, const float* __restrict__ gg,
        const float* __restrict__ bee, const int* __restrict__ batch,
        float* __restrict__ psum_rep) {
    __shared__ __align__(16) _Float16 As[TB][136];
    __shared__ float sh_pool[NLOC][HID];
    int t = threadIdx.x;
    int w = t >> 6, lane = t & 63;
    int slot8 = lane >> 3, q8 = lane & 7;
    int blk = (int)blockIdx.x;
    int nb = blk * TB;

    for (int i = t; i < NLOC * HID; i += 256) ((float*)sh_pool)[i] = 0.f;
    __syncthreads();

    #pragma unroll 1
    for (int i = 0; i < 4; ++i)
        agg_node_fp8(Hin, dinv, row_start, e_pack,
                     nb + w * 4 + i, slot8, q8, &As[w * 4 + i][0]);

    int quad = lane >> 4, r16 = lane & 15;
    int g0 = batch[nb];
    int gi4[4];
    #pragma unroll
    for (int rr = 0; rr < 4; ++rr) gi4[rr] = batch[nb + quad * 4 + rr];
    __syncthreads();

    half8 a[4];
    #pragma unroll
    for (int kb = 0; kb < 4; ++kb)
        a[kb] = *(const half8*)&As[r16][(kb * 4 + quad) * 8];
    float* rep = psum_rep + (size_t)(blk & (NREP - 1)) * N_GRAPHS * HID;
    const float rs = rsqrtf(1.0f + 1e-5f);
    #pragma unroll
    for (int fi = 0; fi < 2; ++fi) {
        int f = (w * 2 + fi) * 16 + r16;
        const half8* Brow = (const half8*)(Wt + (size_t)f * 128);
        float4v acc = {0.f, 0.f, 0.f, 0.f};
        #pragma unroll
        for (int kb = 0; kb < 4; ++kb)
            acc = __builtin_amdgcn_mfma_f32_16x16x32_f16(a[kb], Brow[kb * 4 + quad],
                                                         acc, 0, 0, 0);
        float b0 = bb[f], gf = gg[f] * rs, e0 = bee[f];
        float partial = 0.f;
        int cur = -1;
        #pragma unroll
        for (int rr = 0; rr < 4; ++rr) {
            float v = fmaf(acc[rr] + b0, gf, e0);
            v = v > 0.f ? v : 0.f;
            int gi = gi4[rr];
            if (gi != cur) {
                if (cur >= 0) {
                    int idx = cur - g0;
                    if (idx < NLOC) atomicAdd(&sh_pool[idx][f], partial);
                    else            atomicAdd(&rep[cur * HID + f], partial);
                }
                partial = 0.f; cur = gi;
            }
            partial += v;
        }
        if (cur >= 0) {
            int idx = cur - g0;
            if (idx < NLOC) atomicAdd(&sh_pool[idx][f], partial);
            else            atomicAdd(&rep[cur * HID + f], partial);
        }
    }
    __syncthreads();
    // flush LDS partials: one replicated global atomic per (graph,f) present
    for (int i = t; i < NLOC * HID; i += 256) {
        int idx = i >> 7, ff = i & 127;
        float v = sh_pool[idx][ff];
        int g = g0 + idx;
        if (v != 0.f && g < N_GRAPHS) atomicAdd(&rep[g * HID + ff], v);
    }
}

// ---------- 9. projection (+ graph counts via binary search, no atomics) ----------

__device__ __forceinline__ int lower_bound_batch(const int* __restrict__ batch, int val) {
    int lo = 0, hi = N_NODES;
    while (lo < hi) {
        int mid = (lo + hi) >> 1;
        if (batch[mid] < val) lo = mid + 1;
        else hi = mid;
    }
    return lo;
}

__global__ void k_final(const float* __restrict__ psum_rep, const int* __restrict__ batch,
                        const float* __restrict__ Wp, const float* __restrict__ bp,
                        float* __restrict__ out) {
    __shared__ float s_p[HID];
    int gi = blockIdx.x, e = threadIdx.x;   // 64 threads
    for (int f = e; f < HID; f += EMB) {
        float v = 0.f;
        #pragma unroll
        for (int r = 0; r < NREP; ++r)
            v += psum_rep[(size_t)r * N_GRAPHS * HID + gi * HID + f];
        s_p[f] = v;
    }
    int lane = e & 63;
    int r = 0;
    if (lane < 2) r = lower_bound_batch(batch, gi + lane);
    int c0 = __shfl(r, 0), c1 = __shfl(r, 1);
    float inv = 1.0f / fmaxf((float)(c1 - c0), 1.0f);
    __syncthreads();
    float acc = bp[e];
    #pragma unroll 8
    for (int f = 0; f < HID; ++f)
        acc = fmaf(s_p[f] * inv, Wp[f * EMB + e], acc);
    out[gi * EMB + e] = acc;
}

// ---------- launcher ----------

extern "C" void kernel_launch(void* const* d_in, const int* in_sizes, int n_in,
                              void* d_out, int out_size, void* d_ws, size_t ws_size,
                              hipStream_t stream) {
    const float* x   = (const float*)d_in[0];
    const int*   src = (const int*)d_in[1];
    const int*   dst = (const int*)d_in[2];
    const int* batch = (const int*)d_in[3];
    const float* W1 = (const float*)d_in[4];
    const float* b1 = (const float*)d_in[5];
    const float* W2 = (const float*)d_in[6];
    const float* b2 = (const float*)d_in[7];
    const float* W3 = (const float*)d_in[8];
    const float* b3 = (const float*)d_in[9];
    const float* g1 = (const float*)d_in[10];
    const float* be1 = (const float*)d_in[11];
    const float* g2 = (const float*)d_in[12];
    const float* be2 = (const float*)d_in[13];
    const float* g3 = (const float*)d_in[14];
    const float* be3 = (const float*)d_in[15];
    const float* Wp = (const float*)d_in[16];
    const float* bp = (const float*)d_in[17];
    float* out = (float*)d_out;

    char* ws = (char*)d_ws;
    size_t o = 0;
    auto alloc = [&](size_t bytes) {
        void* pp = ws + o;
        o += bytes;
        o = (o + 255) & ~255ull;
        return pp;
    };
    int*      cnt       = (int*)alloc(N_NODES * 4);
    int*      row_start = (int*)alloc((N_NODES + 1) * 4);
    int*      csum      = (int*)alloc(NCHUNK * 4);
    float*    dinv      = (float*)alloc(N_NODES * 4);
    unsigned int* e_pack = (unsigned int*)alloc((size_t)(N_EDGES + 8) * 4);
    _Float16* Wt2       = (_Float16*)alloc(HID * HID * 2);
    _Float16* Wt3       = (_Float16*)alloc(HID * HID * 2);
    float*    xp        = (float*)alloc((size_t)N_NODES * 8 * 4);
    unsigned int* H8a   = (unsigned int*)alloc((size_t)N_NODES * HID);  // fp8 rows
    unsigned int* H8b   = (unsigned int*)alloc((size_t)N_NODES * HID);
    float*    psum_rep  = (float*)alloc((size_t)NREP * N_GRAPHS * HID * 4);

    k_init<<<(N_NODES + 255) / 256, 256, 0, stream>>>(cnt);
    k_count<<<(N_EDGES + 255) / 256, 256, 0, stream>>>(dst, cnt, psum_rep,
                                                       W2, W3, Wt2, Wt3, e_pack, x, xp);
    k_chunksum<<<NCHUNK, 256, 0, stream>>>(cnt, csum, dinv);
    k_scan<<<NCHUNK, 256, 0, stream>>>(cnt, csum, row_start);
    k_scatter<<<(N_EDGES + 255) / 256, 256, 0, stream>>>(src, dst, dinv, row_start,
                                                         cnt, e_pack);
    k_agg1<<<N_NODES / TB, 256, 0, stream>>>(xp, dinv, row_start, e_pack,
                                             W1, b1, g1, be1, (unsigned short*)H8a);
    k_fuse2<<<N_NODES / TB, 256, 0, stream>>>(H8a, dinv, row_start, e_pack, Wt2,
                                              b2, g2, be2, (unsigned char*)H8b);
    k_fuse3<<<N_NODES / TB, 256, 0, stream>>>(H8b, dinv, row_start, e_pack, Wt3,
                                              b3, g3, be3, batch, psum_rep);
    k_final<<<N_GRAPHS, EMB, 0, stream>>>(psum_rep, batch, Wp, bp, out);
}

// Round 12
// 261.485 us; speedup vs baseline: 1.0968x; 1.0081x over previous
//
#include <hip/hip_runtime.h>
#include <hip/hip_fp16.h>

#define N_NODES 50000
#define N_EDGES 600000
#define N_GRAPHS 64
#define IN_D 5
#define HID 128
#define EMB 64

#define CHUNK 512
#define NCHUNK ((N_NODES + CHUNK - 1) / CHUNK)   // 98
#define NREP 16          // psum replication factor (contention spread)
#define NLOC 4           // per-block local graph slots (16 sorted nodes span <=2)
#define TB 16            // nodes per fused agg+gemm tile (50000 = 3125*16, no tail)

typedef _Float16 half8 __attribute__((ext_vector_type(8)));
typedef float float4v __attribute__((ext_vector_type(4)));
typedef float floatx2 __attribute__((ext_vector_type(2)));

// e_pack entry: fp16(dinv[src]) in high 16 bits | src (fits 16 bits: 50000<65536)
__device__ __forceinline__ float ep_w(unsigned pe) {
    return (float)__ushort_as_half((unsigned short)(pe >> 16));
}
__device__ __forceinline__ unsigned ep_s(unsigned pe) { return pe & 0xffffu; }

// ---------- 1. init: zero cnt (must complete before k_count) ----------

__global__ __launch_bounds__(256) void k_init(int* __restrict__ cnt) {
    int tid = blockIdx.x * blockDim.x + threadIdx.x;
    if (tid < N_NODES) cnt[tid] = 0;
}

// ---------- 2. degree count + independent prep (xp pad, Wt transpose, psum zero) ----------

__global__ __launch_bounds__(256) void k_count(
        const int* __restrict__ dst, int* __restrict__ cnt,
        float* __restrict__ psum_rep,
        const float* __restrict__ W2, const float* __restrict__ W3,
        _Float16* __restrict__ Wt2, _Float16* __restrict__ Wt3,
        unsigned int* __restrict__ e_pack,
        const float* __restrict__ x, float* __restrict__ xp) {
    int tid = blockIdx.x * blockDim.x + threadIdx.x;
    int nt = gridDim.x * blockDim.x;
    if (tid < N_EDGES) atomicAdd(&cnt[dst[tid]], 1);
    if (tid < 8) e_pack[N_EDGES + tid] = 0u;  // safe pad for slot-reads (w=0)
    for (int i = tid; i < NREP * N_GRAPHS * HID; i += nt) psum_rep[i] = 0.f;
    for (int i = tid; i < N_NODES * 8; i += nt) {
        int f = i & 7, n = i >> 3;
        xp[i] = (f < IN_D) ? x[n * IN_D + f] : 0.f;
    }
    for (int i = tid; i < 2 * HID * HID; i += nt) {
        int rem = i & (HID * HID - 1);
        int k = rem & 127, f = rem >> 7;
        if (i < HID * HID) Wt2[rem] = (_Float16)W2[k * HID + f];
        else               Wt3[rem] = (_Float16)W3[k * HID + f];
    }
}

// ---------- 3. per-chunk sums + dinv ----------

__global__ void k_chunksum(const int* __restrict__ cnt, int* __restrict__ csum,
                           float* __restrict__ dinv) {
    __shared__ int sh[256];
    int b = blockIdx.x, t = threadIdx.x;
    int i0 = b * CHUNK + t, i1 = i0 + 256;
    int v = 0;
    if (i0 < N_NODES) { int c = cnt[i0]; v += c; dinv[i0] = rsqrtf((float)c + 1.0f); }
    if (i1 < N_NODES) { int c = cnt[i1]; v += c; dinv[i1] = rsqrtf((float)c + 1.0f); }
    sh[t] = v; __syncthreads();
    for (int off = 128; off > 0; off >>= 1) {
        if (t < off) sh[t] += sh[t + off];
        __syncthreads();
    }
    if (t == 0) csum[b] = sh[0];
}

// ---------- 4. per-chunk exclusive scan -> row_start ----------

__global__ void k_scan(const int* __restrict__ cnt, const int* __restrict__ csum,
                       int* __restrict__ row_start) {
    __shared__ int ws[4];
    int b = blockIdx.x, t = threadIdx.x;
    int lane = t & 63, w = t >> 6;

    int pre = 0;
    for (int j = lane; j < b; j += 64) pre += csum[j];
    #pragma unroll
    for (int off = 32; off > 0; off >>= 1) pre += __shfl_down(pre, off);
    pre = __shfl(pre, 0);

    int base = b * CHUNK;
    int i0 = base + 2 * t, i1 = i0 + 1;
    int c0 = (i0 < N_NODES) ? cnt[i0] : 0;
    int c1 = (i1 < N_NODES) ? cnt[i1] : 0;
    int v = c0 + c1;
    int s = v;
    #pragma unroll
    for (int off = 1; off < 64; off <<= 1) {
        int u = __shfl_up(s, off);
        if (lane >= off) s += u;
    }
    if (lane == 63) ws[w] = s;
    __syncthreads();
    if (t == 0) {
        int r = 0;
        #pragma unroll
        for (int j = 0; j < 4; ++j) { int xx = ws[j]; ws[j] = r; r += xx; }
    }
    __syncthreads();
    int excl = s - v + ws[w] + pre;
    if (i0 < N_NODES) row_start[i0] = excl;
    if (i1 < N_NODES) row_start[i1] = excl + c0;
    if (b == 0 && t == 0) row_start[N_NODES] = N_EDGES;
}

// ---------- 5. scatter edges into CSR order (4B packed records) ----------

__global__ __launch_bounds__(256) void k_scatter(
        const int* __restrict__ src, const int* __restrict__ dst,
        const float* __restrict__ dinv, const int* __restrict__ row_start,
        int* __restrict__ cnt, unsigned int* __restrict__ e_pack) {
    int e = blockIdx.x * blockDim.x + threadIdx.x;
    if (e >= N_EDGES) return;
    int d = dst[e];
    int pos = row_start[d] + atomicSub(&cnt[d], 1) - 1;
    int s = src[e];
    unsigned hw = (unsigned)__half_as_ushort(__float2half(dinv[s]));
    e_pack[pos] = (hw << 16) | (unsigned)s;
}

// ---------- 6. fused layer 1: paired slot-gather agg(xp) + gemm1 + bn + relu -> fp8 ----------
// lane = slot8*8 + q8. Two nodes' e_pack->gather chains kept in flight (R9 win).

__global__ __launch_bounds__(256) void k_agg1(
        const float* __restrict__ xp, const float* __restrict__ dinv,
        const int* __restrict__ row_start, const unsigned int* __restrict__ e_pack,
        const float* __restrict__ W1, const float* __restrict__ b1,
        const float* __restrict__ g1, const float* __restrict__ be1,
        unsigned short* __restrict__ H8u) {
    int t = threadIdx.x;
    int w = t >> 6, lane = t & 63;
    int slot8 = lane >> 3, q8 = lane & 7;
    int nb = blockIdx.x * TB;

    const float rs = rsqrtf(1.0f + 1e-5f);
    int fa = lane * 2, fb = fa + 1;
    float w1a[IN_D], w1b[IN_D];
    #pragma unroll
    for (int k = 0; k < IN_D; ++k) {
        w1a[k] = W1[k * HID + fa];
        w1b[k] = W1[k * HID + fb];
    }
    float b1a = b1[fa], b1b = b1[fb];
    float g1a = g1[fa] * rs, g1b = g1[fb] * rs;
    float e1a = be1[fa], e1b = be1[fb];

    #pragma unroll 1
    for (int i = 0; i < 2; ++i) {
        int n0 = nb + w * 4 + i * 2;
        int beg0 = row_start[n0], end0 = row_start[n0 + 1], end1 = row_start[n0 + 2];
        float acc0 = 0.f, acc1 = 0.f;
        int e0 = beg0, e1 = end0;
        while (e0 < end0 && e1 < end1) {
            unsigned pe0 = e_pack[e0 + slot8];
            unsigned pe1 = e_pack[e1 + slot8];
            float fw0 = (e0 + slot8 < end0) ? ep_w(pe0) : 0.f;
            float fw1 = (e1 + slot8 < end1) ? ep_w(pe1) : 0.f;
            float v0 = xp[(size_t)ep_s(pe0) * 8 + q8];
            float v1 = xp[(size_t)ep_s(pe1) * 8 + q8];
            acc0 = fmaf(fw0, v0, acc0);
            acc1 = fmaf(fw1, v1, acc1);
            e0 += 8; e1 += 8;
        }
        while (e0 < end0) {
            unsigned pe0 = e_pack[e0 + slot8];
            float fw0 = (e0 + slot8 < end0) ? ep_w(pe0) : 0.f;
            acc0 = fmaf(fw0, xp[(size_t)ep_s(pe0) * 8 + q8], acc0);
            e0 += 8;
        }
        while (e1 < end1) {
            unsigned pe1 = e_pack[e1 + slot8];
            float fw1 = (e1 + slot8 < end1) ? ep_w(pe1) : 0.f;
            acc1 = fmaf(fw1, xp[(size_t)ep_s(pe1) * 8 + q8], acc1);
            e1 += 8;
        }
        #pragma unroll
        for (int off = 8; off < 64; off <<= 1) {
            acc0 += __shfl_xor(acc0, off);
            acc1 += __shfl_xor(acc1, off);
        }
        #pragma unroll
        for (int p2 = 0; p2 < 2; ++p2) {
            int n = n0 + p2;
            float accs = p2 ? acc1 : acc0;
            float di = dinv[n];
            float av = di * fmaf(di, xp[(size_t)n * 8 + q8], accs);
            float a0 = __shfl(av, 0), a1 = __shfl(av, 1), a2 = __shfl(av, 2),
                  a3 = __shfl(av, 3), a4 = __shfl(av, 4);
            float va = b1a, vb = b1b;
            va = fmaf(a0, w1a[0], va); vb = fmaf(a0, w1b[0], vb);
            va = fmaf(a1, w1a[1], va); vb = fmaf(a1, w1b[1], vb);
            va = fmaf(a2, w1a[2], va); vb = fmaf(a2, w1b[2], vb);
            va = fmaf(a3, w1a[3], va); vb = fmaf(a3, w1b[3], vb);
            va = fmaf(a4, w1a[4], va); vb = fmaf(a4, w1b[4], vb);
            va = fmaf(va, g1a, e1a);
            vb = fmaf(vb, g1b, e1b);
            va = va > 0.f ? va : 0.f;
            vb = vb > 0.f ? vb : 0.f;
            int p = __builtin_amdgcn_cvt_pk_fp8_f32(va, vb, 0, false);
            H8u[(size_t)n * 64 + lane] = (unsigned short)(p & 0xffff);
        }
    }
}

// ---------- fp8 slot4 agg: 4 edges/inst, 16 lanes/row, 2-level reduce ----------
// lane = slot4*16 + q16: slot4 picks an edge, q16 picks 8 fp8 features (uint2,
// 8B; 16 lanes x 8B = full 128B row, coalesced). Per 4 edges: 1 e_pack inst +
// 1 gather inst. Cross-slot reduce = 8 acc x 2 shfl levels (vs slot8's 16x3 =
// 96 ops -> 32 ops): per-node VALU ~-45%, same line traffic.

__device__ __forceinline__ void agg_node_fp8(
        const unsigned int* __restrict__ H8, const float* __restrict__ dinv,
        const int* __restrict__ row_start, const unsigned int* __restrict__ e_pack,
        int n, int slot4, int q16, _Float16* __restrict__ asrow) {
    float acc[8];
    #pragma unroll
    for (int j = 0; j < 8; ++j) acc[j] = 0.f;
    int beg = row_start[n], end = row_start[n + 1];
    for (int e = beg; e < end; e += 4) {
        unsigned pe = e_pack[e + slot4];
        float fw = (e + slot4 < end) ? ep_w(pe) : 0.f;
        uint2 g = ((const uint2*)(H8 + (size_t)ep_s(pe) * 32))[q16];
        floatx2 l0 = __builtin_amdgcn_cvt_pk_f32_fp8(g.x, false);
        floatx2 h0 = __builtin_amdgcn_cvt_pk_f32_fp8(g.x, true);
        floatx2 l1 = __builtin_amdgcn_cvt_pk_f32_fp8(g.y, false);
        floatx2 h1 = __builtin_amdgcn_cvt_pk_f32_fp8(g.y, true);
        acc[0] = fmaf(fw, l0[0], acc[0]);
        acc[1] = fmaf(fw, l0[1], acc[1]);
        acc[2] = fmaf(fw, h0[0], acc[2]);
        acc[3] = fmaf(fw, h0[1], acc[3]);
        acc[4] = fmaf(fw, l1[0], acc[4]);
        acc[5] = fmaf(fw, l1[1], acc[5]);
        acc[6] = fmaf(fw, h1[0], acc[6]);
        acc[7] = fmaf(fw, h1[1], acc[7]);
    }
    #pragma unroll
    for (int j = 0; j < 8; ++j) {
        float a = acc[j];
        a += __shfl_xor(a, 16);
        a += __shfl_xor(a, 32);
        acc[j] = a;
    }
    if (slot4 == 0) {
        float di = dinv[n];
        uint2 s = ((const uint2*)(H8 + (size_t)n * 32))[q16];
        floatx2 l0 = __builtin_amdgcn_cvt_pk_f32_fp8(s.x, false);
        floatx2 h0 = __builtin_amdgcn_cvt_pk_f32_fp8(s.x, true);
        floatx2 l1 = __builtin_amdgcn_cvt_pk_f32_fp8(s.y, false);
        floatx2 h1 = __builtin_amdgcn_cvt_pk_f32_fp8(s.y, true);
        float sv[8] = {l0[0], l0[1], h0[0], h0[1], l1[0], l1[1], h1[0], h1[1]};
        half8 o;
        #pragma unroll
        for (int j = 0; j < 8; ++j)
            o[j] = (_Float16)(di * fmaf(di, sv[j], acc[j]));
        *(half8*)(asrow + q16 * 8) = o;
    }
}

// ---------- 7. fused layer 2: fp8 agg -> LDS(fp16) -> MFMA + bn + relu -> fp8 ----------

__global__ __launch_bounds__(256) void k_fuse2(
        const unsigned int* __restrict__ Hin, const float* __restrict__ dinv,
        const int* __restrict__ row_start, const unsigned int* __restrict__ e_pack,
        const _Float16* __restrict__ Wt,
        const float* __restrict__ bb, const float* __restrict__ gg,
        const float* __restrict__ bee, unsigned char* __restrict__ out8) {
    __shared__ __align__(16) _Float16 As[TB][136];
    int t = threadIdx.x;
    int w = t >> 6, lane = t & 63;
    int slot4 = lane >> 4, q16 = lane & 15;
    int nb = blockIdx.x * TB;

    #pragma unroll 1
    for (int i = 0; i < 4; ++i)
        agg_node_fp8(Hin, dinv, row_start, e_pack,
                     nb + w * 4 + i, slot4, q16, &As[w * 4 + i][0]);
    __syncthreads();

    int quad = lane >> 4, r16 = lane & 15;
    half8 a[4];
    #pragma unroll
    for (int kb = 0; kb < 4; ++kb)
        a[kb] = *(const half8*)&As[r16][(kb * 4 + quad) * 8];
    const float rs = rsqrtf(1.0f + 1e-5f);
    #pragma unroll
    for (int fi = 0; fi < 2; ++fi) {
        int f = (w * 2 + fi) * 16 + r16;
        const half8* Brow = (const half8*)(Wt + (size_t)f * 128);
        float4v acc = {0.f, 0.f, 0.f, 0.f};
        #pragma unroll
        for (int kb = 0; kb < 4; ++kb)
            acc = __builtin_amdgcn_mfma_f32_16x16x32_f16(a[kb], Brow[kb * 4 + quad],
                                                         acc, 0, 0, 0);
        float b0 = bb[f], gf = gg[f] * rs, e0 = bee[f];
        #pragma unroll
        for (int rr = 0; rr < 4; ++rr) {
            float v = fmaf(acc[rr] + b0, gf, e0);
            v = v > 0.f ? v : 0.f;
            int p = __builtin_amdgcn_cvt_pk_fp8_f32(v, 0.f, 0, false);
            out8[(size_t)(nb + quad * 4 + rr) * 128 + f] = (unsigned char)(p & 0xff);
        }
    }
}

// ---------- 8. fused layer 3: fp8 agg -> MFMA + bn + relu + mean-pool ----------

__global__ __launch_bounds__(256) void k_fuse3(
        const unsigned int* __restrict__ Hin, const float* __restrict__ dinv,
        const int* __restrict__ row_start, const unsigned int* __restrict__ e_pack,
        const _Float16* __restrict__ Wt,
        const float* __restrict__ bb, const float* __restrict__ gg,
        const float* __restrict__ bee, const int* __restrict__ batch,
        float* __restrict__ psum_rep) {
    __shared__ __align__(16) _Float16 As[TB][136];
    __shared__ float sh_pool[NLOC][HID];
    int t = threadIdx.x;
    int w = t >> 6, lane = t & 63;
    int slot4 = lane >> 4, q16 = lane & 15;
    int blk = (int)blockIdx.x;
    int nb = blk * TB;

    for (int i = t; i < NLOC * HID; i += 256) ((float*)sh_pool)[i] = 0.f;
    __syncthreads();

    #pragma unroll 1
    for (int i = 0; i < 4; ++i)
        agg_node_fp8(Hin, dinv, row_start, e_pack,
                     nb + w * 4 + i, slot4, q16, &As[w * 4 + i][0]);

    int quad = lane >> 4, r16 = lane & 15;
    int g0 = batch[nb];
    int gi4[4];
    #pragma unroll
    for (int rr = 0; rr < 4; ++rr) gi4[rr] = batch[nb + quad * 4 + rr];
    __syncthreads();

    half8 a[4];
    #pragma unroll
    for (int kb = 0; kb < 4; ++kb)
        a[kb] = *(const half8*)&As[r16][(kb * 4 + quad) * 8];
    float* rep = psum_rep + (size_t)(blk & (NREP - 1)) * N_GRAPHS * HID;
    const float rs = rsqrtf(1.0f + 1e-5f);
    #pragma unroll
    for (int fi = 0; fi < 2; ++fi) {
        int f = (w * 2 + fi) * 16 + r16;
        const half8* Brow = (const half8*)(Wt + (size_t)f * 128);
        float4v acc = {0.f, 0.f, 0.f, 0.f};
        #pragma unroll
        for (int kb = 0; kb < 4; ++kb)
            acc = __builtin_amdgcn_mfma_f32_16x16x32_f16(a[kb], Brow[kb * 4 + quad],
                                                         acc, 0, 0, 0);
        float b0 = bb[f], gf = gg[f] * rs, e0 = bee[f];
        float partial = 0.f;
        int cur = -1;
        #pragma unroll
        for (int rr = 0; rr < 4; ++rr) {
            float v = fmaf(acc[rr] + b0, gf, e0);
            v = v > 0.f ? v : 0.f;
            int gi = gi4[rr];
            if (gi != cur) {
                if (cur >= 0) {
                    int idx = cur - g0;
                    if (idx < NLOC) atomicAdd(&sh_pool[idx][f], partial);
                    else            atomicAdd(&rep[cur * HID + f], partial);
                }
                partial = 0.f; cur = gi;
            }
            partial += v;
        }
        if (cur >= 0) {
            int idx = cur - g0;
            if (idx < NLOC) atomicAdd(&sh_pool[idx][f], partial);
            else            atomicAdd(&rep[cur * HID + f], partial);
        }
    }
    __syncthreads();
    // flush LDS partials: one replicated global atomic per (graph,f) present
    for (int i = t; i < NLOC * HID; i += 256) {
        int idx = i >> 7, ff = i & 127;
        float v = sh_pool[idx][ff];
        int g = g0 + idx;
        if (v != 0.f && g < N_GRAPHS) atomicAdd(&rep[g * HID + ff], v);
    }
}

// ---------- 9. projection (+ graph counts via binary search, no atomics) ----------

__device__ __forceinline__ int lower_bound_batch(const int* __restrict__ batch, int val) {
    int lo = 0, hi = N_NODES;
    while (lo < hi) {
        int mid = (lo + hi) >> 1;
        if (batch[mid] < val) lo = mid + 1;
        else hi = mid;
    }
    return lo;
}

__global__ void k_final(const float* __restrict__ psum_rep, const int* __restrict__ batch,
                        const float* __restrict__ Wp, const float* __restrict__ bp,
                        float* __restrict__ out) {
    __shared__ float s_p[HID];
    int gi = blockIdx.x, e = threadIdx.x;   // 64 threads
    for (int f = e; f < HID; f += EMB) {
        float v = 0.f;
        #pragma unroll
        for (int r = 0; r < NREP; ++r)
            v += psum_rep[(size_t)r * N_GRAPHS * HID + gi * HID + f];
        s_p[f] = v;
    }
    int lane = e & 63;
    int r = 0;
    if (lane < 2) r = lower_bound_batch(batch, gi + lane);
    int c0 = __shfl(r, 0), c1 = __shfl(r, 1);
    float inv = 1.0f / fmaxf((float)(c1 - c0), 1.0f);
    __syncthreads();
    float acc = bp[e];
    #pragma unroll 8
    for (int f = 0; f < HID; ++f)
        acc = fmaf(s_p[f] * inv, Wp[f * EMB + e], acc);
    out[gi * EMB + e] = acc;
}

// ---------- launcher ----------

extern "C" void kernel_launch(void* const* d_in, const int* in_sizes, int n_in,
                              void* d_out, int out_size, void* d_ws, size_t ws_size,
                              hipStream_t stream) {
    const float* x   = (const float*)d_in[0];
    const int*   src = (const int*)d_in[1];
    const int*   dst = (const int*)d_in[2];
    const int* batch = (const int*)d_in[3];
    const float* W1 = (const float*)d_in[4];
    const float* b1 = (const float*)d_in[5];
    const float* W2 = (const float*)d_in[6];
    const float* b2 = (const float*)d_in[7];
    const float* W3 = (const float*)d_in[8];
    const float* b3 = (const float*)d_in[9];
    const float* g1 = (const float*)d_in[10];
    const float* be1 = (const float*)d_in[11];
    const float* g2 = (const float*)d_in[12];
    const float* be2 = (const float*)d_in[13];
    const float* g3 = (const float*)d_in[14];
    const float* be3 = (const float*)d_in[15];
    const float* Wp = (const float*)d_in[16];
    const float* bp = (const float*)d_in[17];
    float* out = (float*)d_out;

    char* ws = (char*)d_ws;
    size_t o = 0;
    auto alloc = [&](size_t bytes) {
        void* pp = ws + o;
        o += bytes;
        o = (o + 255) & ~255ull;
        return pp;
    };
    int*      cnt       = (int*)alloc(N_NODES * 4);
    int*      row_start = (int*)alloc((N_NODES + 1) * 4);
    int*      csum      = (int*)alloc(NCHUNK * 4);
    float*    dinv      = (float*)alloc(N_NODES * 4);
    unsigned int* e_pack = (unsigned int*)alloc((size_t)(N_EDGES + 8) * 4);
    _Float16* Wt2       = (_Float16*)alloc(HID * HID * 2);
    _Float16* Wt3       = (_Float16*)alloc(HID * HID * 2);
    float*    xp        = (float*)alloc((size_t)N_NODES * 8 * 4);
    unsigned int* H8a   = (unsigned int*)alloc((size_t)N_NODES * HID);  // fp8 rows
    unsigned int* H8b   = (unsigned int*)alloc((size_t)N_NODES * HID);
    float*    psum_rep  = (float*)alloc((size_t)NREP * N_GRAPHS * HID * 4);

    k_init<<<(N_NODES + 255) / 256, 256, 0, stream>>>(cnt);
    k_count<<<(N_EDGES + 255) / 256, 256, 0, stream>>>(dst, cnt, psum_rep,
                                                       W2, W3, Wt2, Wt3, e_pack, x, xp);
    k_chunksum<<<NCHUNK, 256, 0, stream>>>(cnt, csum, dinv);
    k_scan<<<NCHUNK, 256, 0, stream>>>(cnt, csum, row_start);
    k_scatter<<<(N_EDGES + 255) / 256, 256, 0, stream>>>(src, dst, dinv, row_start,
                                                         cnt, e_pack);
    k_agg1<<<N_NODES / TB, 256, 0, stream>>>(xp, dinv, row_start, e_pack,
                                             W1, b1, g1, be1, (unsigned short*)H8a);
    k_fuse2<<<N_NODES / TB, 256, 0, stream>>>(H8a, dinv, row_start, e_pack, Wt2,
                                              b2, g2, be2, (unsigned char*)H8b);
    k_fuse3<<<N_NODES / TB, 256, 0, stream>>>(H8b, dinv, row_start, e_pack, Wt3,
                                              b3, g3, be3, batch, psum_rep);
    k_final<<<N_GRAPHS, EMB, 0, stream>>>(psum_rep, batch, Wp, bp, out);
}

// Round 13
// 250.484 us; speedup vs baseline: 1.1450x; 1.0439x over previous
//
#include <hip/hip_runtime.h>
#include <hip/hip_fp16.h>

#define N_NODES 50000
#define N_EDGES 600000
#define N_GRAPHS 64
#define IN_D 5
#define HID 128
#define EMB 64

#define CHUNK 512
#define NCHUNK ((N_NODES + CHUNK - 1) / CHUNK)   // 98
#define NREP 16          // psum replication factor (contention spread)
#define NLOC 4           // per-block local graph slots (16 sorted nodes span <=2)
#define TB 16            // nodes per fused agg+gemm tile (50000 = 3125*16, no tail)

typedef _Float16 half8 __attribute__((ext_vector_type(8)));
typedef float float4v __attribute__((ext_vector_type(4)));
typedef float floatx2 __attribute__((ext_vector_type(2)));

// e_pack entry: fp16(dinv[src]) in high 16 bits | src (fits 16 bits: 50000<65536)
__device__ __forceinline__ float ep_w(unsigned pe) {
    return (float)__ushort_as_half((unsigned short)(pe >> 16));
}
__device__ __forceinline__ unsigned ep_s(unsigned pe) { return pe & 0xffffu; }

// ---------- 1. init: zero cnt (must complete before k_count) ----------

__global__ __launch_bounds__(256) void k_init(int* __restrict__ cnt) {
    int tid = blockIdx.x * blockDim.x + threadIdx.x;
    if (tid < N_NODES) cnt[tid] = 0;
}

// ---------- 2. degree count + independent prep (xp pad, Wt transpose, psum zero) ----------

__global__ __launch_bounds__(256) void k_count(
        const int* __restrict__ dst, int* __restrict__ cnt,
        float* __restrict__ psum_rep,
        const float* __restrict__ W2, const float* __restrict__ W3,
        _Float16* __restrict__ Wt2, _Float16* __restrict__ Wt3,
        unsigned int* __restrict__ e_pack,
        const float* __restrict__ x, float* __restrict__ xp) {
    int tid = blockIdx.x * blockDim.x + threadIdx.x;
    int nt = gridDim.x * blockDim.x;
    if (tid < N_EDGES) atomicAdd(&cnt[dst[tid]], 1);
    if (tid < 8) e_pack[N_EDGES + tid] = 0u;  // safe pad for slot-reads (w=0)
    for (int i = tid; i < NREP * N_GRAPHS * HID; i += nt) psum_rep[i] = 0.f;
    for (int i = tid; i < N_NODES * 8; i += nt) {
        int f = i & 7, n = i >> 3;
        xp[i] = (f < IN_D) ? x[n * IN_D + f] : 0.f;
    }
    for (int i = tid; i < 2 * HID * HID; i += nt) {
        int rem = i & (HID * HID - 1);
        int k = rem & 127, f = rem >> 7;
        if (i < HID * HID) Wt2[rem] = (_Float16)W2[k * HID + f];
        else               Wt3[rem] = (_Float16)W3[k * HID + f];
    }
}

// ---------- 3. per-chunk sums + dinv ----------

__global__ void k_chunksum(const int* __restrict__ cnt, int* __restrict__ csum,
                           float* __restrict__ dinv) {
    __shared__ int sh[256];
    int b = blockIdx.x, t = threadIdx.x;
    int i0 = b * CHUNK + t, i1 = i0 + 256;
    int v = 0;
    if (i0 < N_NODES) { int c = cnt[i0]; v += c; dinv[i0] = rsqrtf((float)c + 1.0f); }
    if (i1 < N_NODES) { int c = cnt[i1]; v += c; dinv[i1] = rsqrtf((float)c + 1.0f); }
    sh[t] = v; __syncthreads();
    for (int off = 128; off > 0; off >>= 1) {
        if (t < off) sh[t] += sh[t + off];
        __syncthreads();
    }
    if (t == 0) csum[b] = sh[0];
}

// ---------- 4. per-chunk exclusive scan -> row_start ----------

__global__ void k_scan(const int* __restrict__ cnt, const int* __restrict__ csum,
                       int* __restrict__ row_start) {
    __shared__ int ws[4];
    int b = blockIdx.x, t = threadIdx.x;
    int lane = t & 63, w = t >> 6;

    int pre = 0;
    for (int j = lane; j < b; j += 64) pre += csum[j];
    #pragma unroll
    for (int off = 32; off > 0; off >>= 1) pre += __shfl_down(pre, off);
    pre = __shfl(pre, 0);

    int base = b * CHUNK;
    int i0 = base + 2 * t, i1 = i0 + 1;
    int c0 = (i0 < N_NODES) ? cnt[i0] : 0;
    int c1 = (i1 < N_NODES) ? cnt[i1] : 0;
    int v = c0 + c1;
    int s = v;
    #pragma unroll
    for (int off = 1; off < 64; off <<= 1) {
        int u = __shfl_up(s, off);
        if (lane >= off) s += u;
    }
    if (lane == 63) ws[w] = s;
    __syncthreads();
    if (t == 0) {
        int r = 0;
        #pragma unroll
        for (int j = 0; j < 4; ++j) { int xx = ws[j]; ws[j] = r; r += xx; }
    }
    __syncthreads();
    int excl = s - v + ws[w] + pre;
    if (i0 < N_NODES) row_start[i0] = excl;
    if (i1 < N_NODES) row_start[i1] = excl + c0;
    if (b == 0 && t == 0) row_start[N_NODES] = N_EDGES;
}

// ---------- 5. scatter edges into CSR order (4B packed records) ----------

__global__ __launch_bounds__(256) void k_scatter(
        const int* __restrict__ src, const int* __restrict__ dst,
        const float* __restrict__ dinv, const int* __restrict__ row_start,
        int* __restrict__ cnt, unsigned int* __restrict__ e_pack) {
    int e = blockIdx.x * blockDim.x + threadIdx.x;
    if (e >= N_EDGES) return;
    int d = dst[e];
    int pos = row_start[d] + atomicSub(&cnt[d], 1) - 1;
    int s = src[e];
    unsigned hw = (unsigned)__half_as_ushort(__float2half(dinv[s]));
    e_pack[pos] = (hw << 16) | (unsigned)s;
}

// ---------- 6. fused layer 1: paired slot-gather agg(xp) + gemm1 + bn + relu -> fp8 ----------
// lane = slot8*8 + q8. Two nodes' e_pack->gather chains kept in flight (R9 win).

__global__ __launch_bounds__(256) void k_agg1(
        const float* __restrict__ xp, const float* __restrict__ dinv,
        const int* __restrict__ row_start, const unsigned int* __restrict__ e_pack,
        const float* __restrict__ W1, const float* __restrict__ b1,
        const float* __restrict__ g1, const float* __restrict__ be1,
        unsigned short* __restrict__ H8u) {
    int t = threadIdx.x;
    int w = t >> 6, lane = t & 63;
    int slot8 = lane >> 3, q8 = lane & 7;
    int nb = blockIdx.x * TB;

    const float rs = rsqrtf(1.0f + 1e-5f);
    int fa = lane * 2, fb = fa + 1;
    float w1a[IN_D], w1b[IN_D];
    #pragma unroll
    for (int k = 0; k < IN_D; ++k) {
        w1a[k] = W1[k * HID + fa];
        w1b[k] = W1[k * HID + fb];
    }
    float b1a = b1[fa], b1b = b1[fb];
    float g1a = g1[fa] * rs, g1b = g1[fb] * rs;
    float e1a = be1[fa], e1b = be1[fb];

    #pragma unroll 1
    for (int i = 0; i < 2; ++i) {
        int n0 = nb + w * 4 + i * 2;
        int beg0 = row_start[n0], end0 = row_start[n0 + 1], end1 = row_start[n0 + 2];
        float acc0 = 0.f, acc1 = 0.f;
        int e0 = beg0, e1 = end0;
        while (e0 < end0 && e1 < end1) {
            unsigned pe0 = e_pack[e0 + slot8];
            unsigned pe1 = e_pack[e1 + slot8];
            float fw0 = (e0 + slot8 < end0) ? ep_w(pe0) : 0.f;
            float fw1 = (e1 + slot8 < end1) ? ep_w(pe1) : 0.f;
            float v0 = xp[(size_t)ep_s(pe0) * 8 + q8];
            float v1 = xp[(size_t)ep_s(pe1) * 8 + q8];
            acc0 = fmaf(fw0, v0, acc0);
            acc1 = fmaf(fw1, v1, acc1);
            e0 += 8; e1 += 8;
        }
        while (e0 < end0) {
            unsigned pe0 = e_pack[e0 + slot8];
            float fw0 = (e0 + slot8 < end0) ? ep_w(pe0) : 0.f;
            acc0 = fmaf(fw0, xp[(size_t)ep_s(pe0) * 8 + q8], acc0);
            e0 += 8;
        }
        while (e1 < end1) {
            unsigned pe1 = e_pack[e1 + slot8];
            float fw1 = (e1 + slot8 < end1) ? ep_w(pe1) : 0.f;
            acc1 = fmaf(fw1, xp[(size_t)ep_s(pe1) * 8 + q8], acc1);
            e1 += 8;
        }
        #pragma unroll
        for (int off = 8; off < 64; off <<= 1) {
            acc0 += __shfl_xor(acc0, off);
            acc1 += __shfl_xor(acc1, off);
        }
        #pragma unroll
        for (int p2 = 0; p2 < 2; ++p2) {
            int n = n0 + p2;
            float accs = p2 ? acc1 : acc0;
            float di = dinv[n];
            float av = di * fmaf(di, xp[(size_t)n * 8 + q8], accs);
            float a0 = __shfl(av, 0), a1 = __shfl(av, 1), a2 = __shfl(av, 2),
                  a3 = __shfl(av, 3), a4 = __shfl(av, 4);
            float va = b1a, vb = b1b;
            va = fmaf(a0, w1a[0], va); vb = fmaf(a0, w1b[0], vb);
            va = fmaf(a1, w1a[1], va); vb = fmaf(a1, w1b[1], vb);
            va = fmaf(a2, w1a[2], va); vb = fmaf(a2, w1b[2], vb);
            va = fmaf(a3, w1a[3], va); vb = fmaf(a3, w1b[3], vb);
            va = fmaf(a4, w1a[4], va); vb = fmaf(a4, w1b[4], vb);
            va = fmaf(va, g1a, e1a);
            vb = fmaf(vb, g1b, e1b);
            va = va > 0.f ? va : 0.f;
            vb = vb > 0.f ? vb : 0.f;
            int p = __builtin_amdgcn_cvt_pk_fp8_f32(va, vb, 0, false);
            H8u[(size_t)n * 64 + lane] = (unsigned short)(p & 0xffff);
        }
    }
}

// ---------- fp8 slot4 agg, dual-chain: 8 edges/iter as two 4-edge chains ----------
// lane = slot4*16 + q16 (uint2/lane, 16 lanes = full 128B row). Both e_pack
// loads issue back-to-back, both gathers together -> 2 independent chains in
// flight at +~6 VGPR (vs R9's +20 cross-node pairing). 2-level reduce (R12 win).
// B-chain tail reads covered by the 8-entry e_pack pad (weight-masked).

__device__ __forceinline__ void agg_node_fp8(
        const unsigned int* __restrict__ H8, const float* __restrict__ dinv,
        const int* __restrict__ row_start, const unsigned int* __restrict__ e_pack,
        int n, int slot4, int q16, _Float16* __restrict__ asrow) {
    float acc[8];
    #pragma unroll
    for (int j = 0; j < 8; ++j) acc[j] = 0.f;
    int beg = row_start[n], end = row_start[n + 1];
    for (int e = beg; e < end; e += 8) {
        unsigned peA = e_pack[e + slot4];
        unsigned peB = e_pack[e + 4 + slot4];         // pad-safe (<= N_EDGES+7)
        float fwA = (e + slot4 < end) ? ep_w(peA) : 0.f;
        float fwB = (e + 4 + slot4 < end) ? ep_w(peB) : 0.f;
        uint2 gA = ((const uint2*)(H8 + (size_t)ep_s(peA) * 32))[q16];
        uint2 gB = ((const uint2*)(H8 + (size_t)ep_s(peB) * 32))[q16];
        {
            floatx2 l0 = __builtin_amdgcn_cvt_pk_f32_fp8(gA.x, false);
            floatx2 h0 = __builtin_amdgcn_cvt_pk_f32_fp8(gA.x, true);
            floatx2 l1 = __builtin_amdgcn_cvt_pk_f32_fp8(gA.y, false);
            floatx2 h1 = __builtin_amdgcn_cvt_pk_f32_fp8(gA.y, true);
            acc[0] = fmaf(fwA, l0[0], acc[0]);
            acc[1] = fmaf(fwA, l0[1], acc[1]);
            acc[2] = fmaf(fwA, h0[0], acc[2]);
            acc[3] = fmaf(fwA, h0[1], acc[3]);
            acc[4] = fmaf(fwA, l1[0], acc[4]);
            acc[5] = fmaf(fwA, l1[1], acc[5]);
            acc[6] = fmaf(fwA, h1[0], acc[6]);
            acc[7] = fmaf(fwA, h1[1], acc[7]);
        }
        {
            floatx2 l0 = __builtin_amdgcn_cvt_pk_f32_fp8(gB.x, false);
            floatx2 h0 = __builtin_amdgcn_cvt_pk_f32_fp8(gB.x, true);
            floatx2 l1 = __builtin_amdgcn_cvt_pk_f32_fp8(gB.y, false);
            floatx2 h1 = __builtin_amdgcn_cvt_pk_f32_fp8(gB.y, true);
            acc[0] = fmaf(fwB, l0[0], acc[0]);
            acc[1] = fmaf(fwB, l0[1], acc[1]);
            acc[2] = fmaf(fwB, h0[0], acc[2]);
            acc[3] = fmaf(fwB, h0[1], acc[3]);
            acc[4] = fmaf(fwB, l1[0], acc[4]);
            acc[5] = fmaf(fwB, l1[1], acc[5]);
            acc[6] = fmaf(fwB, h1[0], acc[6]);
            acc[7] = fmaf(fwB, h1[1], acc[7]);
        }
    }
    #pragma unroll
    for (int j = 0; j < 8; ++j) {
        float a = acc[j];
        a += __shfl_xor(a, 16);
        a += __shfl_xor(a, 32);
        acc[j] = a;
    }
    if (slot4 == 0) {
        float di = dinv[n];
        uint2 s = ((const uint2*)(H8 + (size_t)n * 32))[q16];
        floatx2 l0 = __builtin_amdgcn_cvt_pk_f32_fp8(s.x, false);
        floatx2 h0 = __builtin_amdgcn_cvt_pk_f32_fp8(s.x, true);
        floatx2 l1 = __builtin_amdgcn_cvt_pk_f32_fp8(s.y, false);
        floatx2 h1 = __builtin_amdgcn_cvt_pk_f32_fp8(s.y, true);
        float sv[8] = {l0[0], l0[1], h0[0], h0[1], l1[0], l1[1], h1[0], h1[1]};
        half8 o;
        #pragma unroll
        for (int j = 0; j < 8; ++j)
            o[j] = (_Float16)(di * fmaf(di, sv[j], acc[j]));
        *(half8*)(asrow + q16 * 8) = o;
    }
}

// ---------- 7. fused layer 2: fp8 agg -> LDS(fp16) -> MFMA + bn + relu -> fp8 ----------

__global__ __launch_bounds__(256) void k_fuse2(
        const unsigned int* __restrict__ Hin, const float* __restrict__ dinv,
        const int* __restrict__ row_start, const unsigned int* __restrict__ e_pack,
        const _Float16* __restrict__ Wt,
        const float* __restrict__ bb, const float* __restrict__ gg,
        const float* __restrict__ bee, unsigned char* __restrict__ out8) {
    __shared__ __align__(16) _Float16 As[TB][136];
    int t = threadIdx.x;
    int w = t >> 6, lane = t & 63;
    int slot4 = lane >> 4, q16 = lane & 15;
    int nb = blockIdx.x * TB;

    #pragma unroll 1
    for (int i = 0; i < 4; ++i)
        agg_node_fp8(Hin, dinv, row_start, e_pack,
                     nb + w * 4 + i, slot4, q16, &As[w * 4 + i][0]);
    __syncthreads();

    int quad = lane >> 4, r16 = lane & 15;
    half8 a[4];
    #pragma unroll
    for (int kb = 0; kb < 4; ++kb)
        a[kb] = *(const half8*)&As[r16][(kb * 4 + quad) * 8];
    const float rs = rsqrtf(1.0f + 1e-5f);
    #pragma unroll
    for (int fi = 0; fi < 2; ++fi) {
        int f = (w * 2 + fi) * 16 + r16;
        const half8* Brow = (const half8*)(Wt + (size_t)f * 128);
        float4v acc = {0.f, 0.f, 0.f, 0.f};
        #pragma unroll
        for (int kb = 0; kb < 4; ++kb)
            acc = __builtin_amdgcn_mfma_f32_16x16x32_f16(a[kb], Brow[kb * 4 + quad],
                                                         acc, 0, 0, 0);
        float b0 = bb[f], gf = gg[f] * rs, e0 = bee[f];
        #pragma unroll
        for (int rr = 0; rr < 4; ++rr) {
            float v = fmaf(acc[rr] + b0, gf, e0);
            v = v > 0.f ? v : 0.f;
            int p = __builtin_amdgcn_cvt_pk_fp8_f32(v, 0.f, 0, false);
            out8[(size_t)(nb + quad * 4 + rr) * 128 + f] = (unsigned char)(p & 0xff);
        }
    }
}

// ---------- 8. fused layer 3: fp8 agg -> MFMA + bn + relu + mean-pool ----------

__global__ __launch_bounds__(256) void k_fuse3(
        const unsigned int* __restrict__ Hin, const float* __restrict__ dinv,
        const int* __restrict__ row_start, const unsigned int* __restrict__ e_pack,
        const _Float16* __restrict__ Wt,
        const float* __restrict__ bb, const float* __restrict__ gg,
        const float* __restrict__ bee, const int* __restrict__ batch,
        float* __restrict__ psum_rep) {
    __shared__ __align__(16) _Float16 As[TB][136];
    __shared__ float sh_pool[NLOC][HID];
    int t = threadIdx.x;
    int w = t >> 6, lane = t & 63;
    int slot4 = lane >> 4, q16 = lane & 15;
    int blk = (int)blockIdx.x;
    int nb = blk * TB;

    for (int i = t; i < NLOC * HID; i += 256) ((float*)sh_pool)[i] = 0.f;
    __syncthreads();

    #pragma unroll 1
    for (int i = 0; i < 4; ++i)
        agg_node_fp8(Hin, dinv, row_start, e_pack,
                     nb + w * 4 + i, slot4, q16, &As[w * 4 + i][0]);

    int quad = lane >> 4, r16 = lane & 15;
    int g0 = batch[nb];
    int gi4[4];
    #pragma unroll
    for (int rr = 0; rr < 4; ++rr) gi4[rr] = batch[nb + quad * 4 + rr];
    __syncthreads();

    half8 a[4];
    #pragma unroll
    for (int kb = 0; kb < 4; ++kb)
        a[kb] = *(const half8*)&As[r16][(kb * 4 + quad) * 8];
    float* rep = psum_rep + (size_t)(blk & (NREP - 1)) * N_GRAPHS * HID;
    const float rs = rsqrtf(1.0f + 1e-5f);
    #pragma unroll
    for (int fi = 0; fi < 2; ++fi) {
        int f = (w * 2 + fi) * 16 + r16;
        const half8* Brow = (const half8*)(Wt + (size_t)f * 128);
        float4v acc = {0.f, 0.f, 0.f, 0.f};
        #pragma unroll
        for (int kb = 0; kb < 4; ++kb)
            acc = __builtin_amdgcn_mfma_f32_16x16x32_f16(a[kb], Brow[kb * 4 + quad],
                                                         acc, 0, 0, 0);
        float b0 = bb[f], gf = gg[f] * rs, e0 = bee[f];
        float partial = 0.f;
        int cur = -1;
        #pragma unroll
        for (int rr = 0; rr < 4; ++rr) {
            float v = fmaf(acc[rr] + b0, gf, e0);
            v = v > 0.f ? v : 0.f;
            int gi = gi4[rr];
            if (gi != cur) {
                if (cur >= 0) {
                    int idx = cur - g0;
                    if (idx < NLOC) atomicAdd(&sh_pool[idx][f], partial);
                    else            atomicAdd(&rep[cur * HID + f], partial);
                }
                partial = 0.f; cur = gi;
            }
            partial += v;
        }
        if (cur >= 0) {
            int idx = cur - g0;
            if (idx < NLOC) atomicAdd(&sh_pool[idx][f], partial);
            else            atomicAdd(&rep[cur * HID + f], partial);
        }
    }
    __syncthreads();
    // flush LDS partials: one replicated global atomic per (graph,f) present
    for (int i = t; i < NLOC * HID; i += 256) {
        int idx = i >> 7, ff = i & 127;
        float v = sh_pool[idx][ff];
        int g = g0 + idx;
        if (v != 0.f && g < N_GRAPHS) atomicAdd(&rep[g * HID + ff], v);
    }
}

// ---------- 9. projection (+ graph counts via binary search, no atomics) ----------

__device__ __forceinline__ int lower_bound_batch(const int* __restrict__ batch, int val) {
    int lo = 0, hi = N_NODES;
    while (lo < hi) {
        int mid = (lo + hi) >> 1;
        if (batch[mid] < val) lo = mid + 1;
        else hi = mid;
    }
    return lo;
}

__global__ void k_final(const float* __restrict__ psum_rep, const int* __restrict__ batch,
                        const float* __restrict__ Wp, const float* __restrict__ bp,
                        float* __restrict__ out) {
    __shared__ float s_p[HID];
    int gi = blockIdx.x, e = threadIdx.x;   // 64 threads
    for (int f = e; f < HID; f += EMB) {
        float v = 0.f;
        #pragma unroll
        for (int r = 0; r < NREP; ++r)
            v += psum_rep[(size_t)r * N_GRAPHS * HID + gi * HID + f];
        s_p[f] = v;
    }
    int lane = e & 63;
    int r = 0;
    if (lane < 2) r = lower_bound_batch(batch, gi + lane);
    int c0 = __shfl(r, 0), c1 = __shfl(r, 1);
    float inv = 1.0f / fmaxf((float)(c1 - c0), 1.0f);
    __syncthreads();
    float acc = bp[e];
    #pragma unroll 8
    for (int f = 0; f < HID; ++f)
        acc = fmaf(s_p[f] * inv, Wp[f * EMB + e], acc);
    out[gi * EMB + e] = acc;
}

// ---------- launcher ----------

extern "C" void kernel_launch(void* const* d_in, const int* in_sizes, int n_in,
                              void* d_out, int out_size, void* d_ws, size_t ws_size,
                              hipStream_t stream) {
    const float* x   = (const float*)d_in[0];
    const int*   src = (const int*)d_in[1];
    const int*   dst = (const int*)d_in[2];
    const int* batch = (const int*)d_in[3];
    const float* W1 = (const float*)d_in[4];
    const float* b1 = (const float*)d_in[5];
    const float* W2 = (const float*)d_in[6];
    const float* b2 = (const float*)d_in[7];
    const float* W3 = (const float*)d_in[8];
    const float* b3 = (const float*)d_in[9];
    const float* g1 = (const float*)d_in[10];
    const float* be1 = (const float*)d_in[11];
    const float* g2 = (const float*)d_in[12];
    const float* be2 = (const float*)d_in[13];
    const float* g3 = (const float*)d_in[14];
    const float* be3 = (const float*)d_in[15];
    const float* Wp = (const float*)d_in[16];
    const float* bp = (const float*)d_in[17];
    float* out = (float*)d_out;

    char* ws = (char*)d_ws;
    size_t o = 0;
    auto alloc = [&](size_t bytes) {
        void* pp = ws + o;
        o += bytes;
        o = (o + 255) & ~255ull;
        return pp;
    };
    int*      cnt       = (int*)alloc(N_NODES * 4);
    int*      row_start = (int*)alloc((N_NODES + 1) * 4);
    int*      csum      = (int*)alloc(NCHUNK * 4);
    float*    dinv      = (float*)alloc(N_NODES * 4);
    unsigned int* e_pack = (unsigned int*)alloc((size_t)(N_EDGES + 8) * 4);
    _Float16* Wt2       = (_Float16*)alloc(HID * HID * 2);
    _Float16* Wt3       = (_Float16*)alloc(HID * HID * 2);
    float*    xp        = (float*)alloc((size_t)N_NODES * 8 * 4);
    unsigned int* H8a   = (unsigned int*)alloc((size_t)N_NODES * HID);  // fp8 rows
    unsigned int* H8b   = (unsigned int*)alloc((size_t)N_NODES * HID);
    float*    psum_rep  = (float*)alloc((size_t)NREP * N_GRAPHS * HID * 4);

    k_init<<<(N_NODES + 255) / 256, 256, 0, stream>>>(cnt);
    k_count<<<(N_EDGES + 255) / 256, 256, 0, stream>>>(dst, cnt, psum_rep,
                                                       W2, W3, Wt2, Wt3, e_pack, x, xp);
    k_chunksum<<<NCHUNK, 256, 0, stream>>>(cnt, csum, dinv);
    k_scan<<<NCHUNK, 256, 0, stream>>>(cnt, csum, row_start);
    k_scatter<<<(N_EDGES + 255) / 256, 256, 0, stream>>>(src, dst, dinv, row_start,
                                                         cnt, e_pack);
    k_agg1<<<N_NODES / TB, 256, 0, stream>>>(xp, dinv, row_start, e_pack,
                                             W1, b1, g1, be1, (unsigned short*)H8a);
    k_fuse2<<<N_NODES / TB, 256, 0, stream>>>(H8a, dinv, row_start, e_pack, Wt2,
                                              b2, g2, be2, (unsigned char*)H8b);
    k_fuse3<<<N_NODES / TB, 256, 0, stream>>>(H8b, dinv, row_start, e_pack, Wt3,
                                              b3, g3, be3, batch, psum_rep);
    k_final<<<N_GRAPHS, EMB, 0, stream>>>(psum_rep, batch, Wp, bp, out);
}

// Round 14
// 244.812 us; speedup vs baseline: 1.1715x; 1.0232x over previous
//
#include <hip/hip_runtime.h>
#include <hip/hip_fp16.h>

#define N_NODES 50000
#define N_EDGES 600000
#define N_GRAPHS 64
#define IN_D 5
#define HID 128
#define EMB 64

#define CHUNK 512
#define NCHUNK ((N_NODES + CHUNK - 1) / CHUNK)   // 98
#define NREP 16          // psum replication factor (contention spread)
#define NLOC 4           // per-block local graph slots (16 sorted nodes span <=2)
#define TB 16            // nodes per fused agg+gemm tile (50000 = 3125*16, no tail)

typedef _Float16 half8 __attribute__((ext_vector_type(8)));
typedef float float4v __attribute__((ext_vector_type(4)));
typedef float floatx2 __attribute__((ext_vector_type(2)));

// e_pack entry: fp16(dinv[src]) in high 16 bits | src (fits 16 bits: 50000<65536)
__device__ __forceinline__ float ep_w(unsigned pe) {
    return (float)__ushort_as_half((unsigned short)(pe >> 16));
}
__device__ __forceinline__ unsigned ep_s(unsigned pe) { return pe & 0xffffu; }

// ---------- 1. init: zero cnt (must complete before k_count) ----------

__global__ __launch_bounds__(256) void k_init(int* __restrict__ cnt) {
    int tid = blockIdx.x * blockDim.x + threadIdx.x;
    if (tid < N_NODES) cnt[tid] = 0;
}

// ---------- 2. degree count + independent prep (xp pad, Wt transpose, psum zero) ----------

__global__ __launch_bounds__(256) void k_count(
        const int* __restrict__ dst, int* __restrict__ cnt,
        float* __restrict__ psum_rep,
        const float* __restrict__ W2, const float* __restrict__ W3,
        _Float16* __restrict__ Wt2, _Float16* __restrict__ Wt3,
        unsigned int* __restrict__ e_pack,
        const float* __restrict__ x, float* __restrict__ xp) {
    int tid = blockIdx.x * blockDim.x + threadIdx.x;
    int nt = gridDim.x * blockDim.x;
    if (tid < N_EDGES) atomicAdd(&cnt[dst[tid]], 1);
    if (tid < 16) e_pack[N_EDGES + tid] = 0u;  // safe pad (quad-chain reads +15)
    for (int i = tid; i < NREP * N_GRAPHS * HID; i += nt) psum_rep[i] = 0.f;
    for (int i = tid; i < N_NODES * 8; i += nt) {
        int f = i & 7, n = i >> 3;
        xp[i] = (f < IN_D) ? x[n * IN_D + f] : 0.f;
    }
    for (int i = tid; i < 2 * HID * HID; i += nt) {
        int rem = i & (HID * HID - 1);
        int k = rem & 127, f = rem >> 7;
        if (i < HID * HID) Wt2[rem] = (_Float16)W2[k * HID + f];
        else               Wt3[rem] = (_Float16)W3[k * HID + f];
    }
}

// ---------- 3. per-chunk sums + dinv ----------

__global__ void k_chunksum(const int* __restrict__ cnt, int* __restrict__ csum,
                           float* __restrict__ dinv) {
    __shared__ int sh[256];
    int b = blockIdx.x, t = threadIdx.x;
    int i0 = b * CHUNK + t, i1 = i0 + 256;
    int v = 0;
    if (i0 < N_NODES) { int c = cnt[i0]; v += c; dinv[i0] = rsqrtf((float)c + 1.0f); }
    if (i1 < N_NODES) { int c = cnt[i1]; v += c; dinv[i1] = rsqrtf((float)c + 1.0f); }
    sh[t] = v; __syncthreads();
    for (int off = 128; off > 0; off >>= 1) {
        if (t < off) sh[t] += sh[t + off];
        __syncthreads();
    }
    if (t == 0) csum[b] = sh[0];
}

// ---------- 4. per-chunk exclusive scan -> row_start ----------

__global__ void k_scan(const int* __restrict__ cnt, const int* __restrict__ csum,
                       int* __restrict__ row_start) {
    __shared__ int ws[4];
    int b = blockIdx.x, t = threadIdx.x;
    int lane = t & 63, w = t >> 6;

    int pre = 0;
    for (int j = lane; j < b; j += 64) pre += csum[j];
    #pragma unroll
    for (int off = 32; off > 0; off >>= 1) pre += __shfl_down(pre, off);
    pre = __shfl(pre, 0);

    int base = b * CHUNK;
    int i0 = base + 2 * t, i1 = i0 + 1;
    int c0 = (i0 < N_NODES) ? cnt[i0] : 0;
    int c1 = (i1 < N_NODES) ? cnt[i1] : 0;
    int v = c0 + c1;
    int s = v;
    #pragma unroll
    for (int off = 1; off < 64; off <<= 1) {
        int u = __shfl_up(s, off);
        if (lane >= off) s += u;
    }
    if (lane == 63) ws[w] = s;
    __syncthreads();
    if (t == 0) {
        int r = 0;
        #pragma unroll
        for (int j = 0; j < 4; ++j) { int xx = ws[j]; ws[j] = r; r += xx; }
    }
    __syncthreads();
    int excl = s - v + ws[w] + pre;
    if (i0 < N_NODES) row_start[i0] = excl;
    if (i1 < N_NODES) row_start[i1] = excl + c0;
    if (b == 0 && t == 0) row_start[N_NODES] = N_EDGES;
}

// ---------- 5. scatter edges into CSR order (4B packed records) ----------

__global__ __launch_bounds__(256) void k_scatter(
        const int* __restrict__ src, const int* __restrict__ dst,
        const float* __restrict__ dinv, const int* __restrict__ row_start,
        int* __restrict__ cnt, unsigned int* __restrict__ e_pack) {
    int e = blockIdx.x * blockDim.x + threadIdx.x;
    if (e >= N_EDGES) return;
    int d = dst[e];
    int pos = row_start[d] + atomicSub(&cnt[d], 1) - 1;
    int s = src[e];
    unsigned hw = (unsigned)__half_as_ushort(__float2half(dinv[s]));
    e_pack[pos] = (hw << 16) | (unsigned)s;
}

// ---------- 6. fused layer 1: paired slot-gather agg(xp) + gemm1 + bn + relu -> fp8 ----------
// lane = slot8*8 + q8. Two nodes' e_pack->gather chains kept in flight (R9 win).

__global__ __launch_bounds__(256) void k_agg1(
        const float* __restrict__ xp, const float* __restrict__ dinv,
        const int* __restrict__ row_start, const unsigned int* __restrict__ e_pack,
        const float* __restrict__ W1, const float* __restrict__ b1,
        const float* __restrict__ g1, const float* __restrict__ be1,
        unsigned short* __restrict__ H8u) {
    int t = threadIdx.x;
    int w = t >> 6, lane = t & 63;
    int slot8 = lane >> 3, q8 = lane & 7;
    int nb = blockIdx.x * TB;

    const float rs = rsqrtf(1.0f + 1e-5f);
    int fa = lane * 2, fb = fa + 1;
    float w1a[IN_D], w1b[IN_D];
    #pragma unroll
    for (int k = 0; k < IN_D; ++k) {
        w1a[k] = W1[k * HID + fa];
        w1b[k] = W1[k * HID + fb];
    }
    float b1a = b1[fa], b1b = b1[fb];
    float g1a = g1[fa] * rs, g1b = g1[fb] * rs;
    float e1a = be1[fa], e1b = be1[fb];

    #pragma unroll 1
    for (int i = 0; i < 2; ++i) {
        int n0 = nb + w * 4 + i * 2;
        int beg0 = row_start[n0], end0 = row_start[n0 + 1], end1 = row_start[n0 + 2];
        float acc0 = 0.f, acc1 = 0.f;
        int e0 = beg0, e1 = end0;
        while (e0 < end0 && e1 < end1) {
            unsigned pe0 = e_pack[e0 + slot8];
            unsigned pe1 = e_pack[e1 + slot8];
            float fw0 = (e0 + slot8 < end0) ? ep_w(pe0) : 0.f;
            float fw1 = (e1 + slot8 < end1) ? ep_w(pe1) : 0.f;
            float v0 = xp[(size_t)ep_s(pe0) * 8 + q8];
            float v1 = xp[(size_t)ep_s(pe1) * 8 + q8];
            acc0 = fmaf(fw0, v0, acc0);
            acc1 = fmaf(fw1, v1, acc1);
            e0 += 8; e1 += 8;
        }
        while (e0 < end0) {
            unsigned pe0 = e_pack[e0 + slot8];
            float fw0 = (e0 + slot8 < end0) ? ep_w(pe0) : 0.f;
            acc0 = fmaf(fw0, xp[(size_t)ep_s(pe0) * 8 + q8], acc0);
            e0 += 8;
        }
        while (e1 < end1) {
            unsigned pe1 = e_pack[e1 + slot8];
            float fw1 = (e1 + slot8 < end1) ? ep_w(pe1) : 0.f;
            acc1 = fmaf(fw1, xp[(size_t)ep_s(pe1) * 8 + q8], acc1);
            e1 += 8;
        }
        #pragma unroll
        for (int off = 8; off < 64; off <<= 1) {
            acc0 += __shfl_xor(acc0, off);
            acc1 += __shfl_xor(acc1, off);
        }
        #pragma unroll
        for (int p2 = 0; p2 < 2; ++p2) {
            int n = n0 + p2;
            float accs = p2 ? acc1 : acc0;
            float di = dinv[n];
            float av = di * fmaf(di, xp[(size_t)n * 8 + q8], accs);
            float a0 = __shfl(av, 0), a1 = __shfl(av, 1), a2 = __shfl(av, 2),
                  a3 = __shfl(av, 3), a4 = __shfl(av, 4);
            float va = b1a, vb = b1b;
            va = fmaf(a0, w1a[0], va); vb = fmaf(a0, w1b[0], vb);
            va = fmaf(a1, w1a[1], va); vb = fmaf(a1, w1b[1], vb);
            va = fmaf(a2, w1a[2], va); vb = fmaf(a2, w1b[2], vb);
            va = fmaf(a3, w1a[3], va); vb = fmaf(a3, w1b[3], vb);
            va = fmaf(a4, w1a[4], va); vb = fmaf(a4, w1b[4], vb);
            va = fmaf(va, g1a, e1a);
            vb = fmaf(vb, g1b, e1b);
            va = va > 0.f ? va : 0.f;
            vb = vb > 0.f ? vb : 0.f;
            int p = __builtin_amdgcn_cvt_pk_fp8_f32(va, vb, 0, false);
            H8u[(size_t)n * 64 + lane] = (unsigned short)(p & 0xffff);
        }
    }
}

// ---------- fp8 slot4 agg, quad-chain: 16 edges/iter as four 4-edge chains ----------
// lane = slot4*16 + q16 (uint2/lane, 16 lanes = full 128B row). Four e_pack
// loads issue back-to-back, four gathers together -> 4 independent chains in
// flight, shared acc[8], 2-level reduce. VGPR ~50 < 64 step (no occupancy
// cliff, m69). Tail slots read the 16-entry pad (weight-masked).

__device__ __forceinline__ void acc8_fp8(float* __restrict__ acc, float fw, uint2 g) {
    floatx2 l0 = __builtin_amdgcn_cvt_pk_f32_fp8(g.x, false);
    floatx2 h0 = __builtin_amdgcn_cvt_pk_f32_fp8(g.x, true);
    floatx2 l1 = __builtin_amdgcn_cvt_pk_f32_fp8(g.y, false);
    floatx2 h1 = __builtin_amdgcn_cvt_pk_f32_fp8(g.y, true);
    acc[0] = fmaf(fw, l0[0], acc[0]);
    acc[1] = fmaf(fw, l0[1], acc[1]);
    acc[2] = fmaf(fw, h0[0], acc[2]);
    acc[3] = fmaf(fw, h0[1], acc[3]);
    acc[4] = fmaf(fw, l1[0], acc[4]);
    acc[5] = fmaf(fw, l1[1], acc[5]);
    acc[6] = fmaf(fw, h1[0], acc[6]);
    acc[7] = fmaf(fw, h1[1], acc[7]);
}

__device__ __forceinline__ void agg_node_fp8(
        const unsigned int* __restrict__ H8, const float* __restrict__ dinv,
        const int* __restrict__ row_start, const unsigned int* __restrict__ e_pack,
        int n, int slot4, int q16, _Float16* __restrict__ asrow) {
    float acc[8];
    #pragma unroll
    for (int j = 0; j < 8; ++j) acc[j] = 0.f;
    int beg = row_start[n], end = row_start[n + 1];
    for (int e = beg; e < end; e += 16) {
        unsigned peA = e_pack[e + slot4];
        unsigned peB = e_pack[e + 4 + slot4];
        unsigned peC = e_pack[e + 8 + slot4];
        unsigned peD = e_pack[e + 12 + slot4];        // pad-safe (<= N_EDGES+15)
        float fwA = (e + slot4 < end) ? ep_w(peA) : 0.f;
        float fwB = (e + 4 + slot4 < end) ? ep_w(peB) : 0.f;
        float fwC = (e + 8 + slot4 < end) ? ep_w(peC) : 0.f;
        float fwD = (e + 12 + slot4 < end) ? ep_w(peD) : 0.f;
        uint2 gA = ((const uint2*)(H8 + (size_t)ep_s(peA) * 32))[q16];
        uint2 gB = ((const uint2*)(H8 + (size_t)ep_s(peB) * 32))[q16];
        uint2 gC = ((const uint2*)(H8 + (size_t)ep_s(peC) * 32))[q16];
        uint2 gD = ((const uint2*)(H8 + (size_t)ep_s(peD) * 32))[q16];
        acc8_fp8(acc, fwA, gA);
        acc8_fp8(acc, fwB, gB);
        acc8_fp8(acc, fwC, gC);
        acc8_fp8(acc, fwD, gD);
    }
    #pragma unroll
    for (int j = 0; j < 8; ++j) {
        float a = acc[j];
        a += __shfl_xor(a, 16);
        a += __shfl_xor(a, 32);
        acc[j] = a;
    }
    if (slot4 == 0) {
        float di = dinv[n];
        uint2 s = ((const uint2*)(H8 + (size_t)n * 32))[q16];
        floatx2 l0 = __builtin_amdgcn_cvt_pk_f32_fp8(s.x, false);
        floatx2 h0 = __builtin_amdgcn_cvt_pk_f32_fp8(s.x, true);
        floatx2 l1 = __builtin_amdgcn_cvt_pk_f32_fp8(s.y, false);
        floatx2 h1 = __builtin_amdgcn_cvt_pk_f32_fp8(s.y, true);
        float sv[8] = {l0[0], l0[1], h0[0], h0[1], l1[0], l1[1], h1[0], h1[1]};
        half8 o;
        #pragma unroll
        for (int j = 0; j < 8; ++j)
            o[j] = (_Float16)(di * fmaf(di, sv[j], acc[j]));
        *(half8*)(asrow + q16 * 8) = o;
    }
}

// ---------- 7. fused layer 2: fp8 agg -> LDS(fp16) -> MFMA + bn + relu -> fp8 ----------

__global__ __launch_bounds__(256) void k_fuse2(
        const unsigned int* __restrict__ Hin, const float* __restrict__ dinv,
        const int* __restrict__ row_start, const unsigned int* __restrict__ e_pack,
        const _Float16* __restrict__ Wt,
        const float* __restrict__ bb, const float* __restrict__ gg,
        const float* __restrict__ bee, unsigned char* __restrict__ out8) {
    __shared__ __align__(16) _Float16 As[TB][136];
    int t = threadIdx.x;
    int w = t >> 6, lane = t & 63;
    int slot4 = lane >> 4, q16 = lane & 15;
    int nb = blockIdx.x * TB;

    #pragma unroll 1
    for (int i = 0; i < 4; ++i)
        agg_node_fp8(Hin, dinv, row_start, e_pack,
                     nb + w * 4 + i, slot4, q16, &As[w * 4 + i][0]);
    __syncthreads();

    int quad = lane >> 4, r16 = lane & 15;
    half8 a[4];
    #pragma unroll
    for (int kb = 0; kb < 4; ++kb)
        a[kb] = *(const half8*)&As[r16][(kb * 4 + quad) * 8];
    const float rs = rsqrtf(1.0f + 1e-5f);
    #pragma unroll
    for (int fi = 0; fi < 2; ++fi) {
        int f = (w * 2 + fi) * 16 + r16;
        const half8* Brow = (const half8*)(Wt + (size_t)f * 128);
        float4v acc = {0.f, 0.f, 0.f, 0.f};
        #pragma unroll
        for (int kb = 0; kb < 4; ++kb)
            acc = __builtin_amdgcn_mfma_f32_16x16x32_f16(a[kb], Brow[kb * 4 + quad],
                                                         acc, 0, 0, 0);
        float b0 = bb[f], gf = gg[f] * rs, e0 = bee[f];
        #pragma unroll
        for (int rr = 0; rr < 4; ++rr) {
            float v = fmaf(acc[rr] + b0, gf, e0);
            v = v > 0.f ? v : 0.f;
            int p = __builtin_amdgcn_cvt_pk_fp8_f32(v, 0.f, 0, false);
            out8[(size_t)(nb + quad * 4 + rr) * 128 + f] = (unsigned char)(p & 0xff);
        }
    }
}

// ---------- 8. fused layer 3: fp8 agg -> MFMA + bn + relu + mean-pool ----------

__global__ __launch_bounds__(256) void k_fuse3(
        const unsigned int* __restrict__ Hin, const float* __restrict__ dinv,
        const int* __restrict__ row_start, const unsigned int* __restrict__ e_pack,
        const _Float16* __restrict__ Wt,
        const float* __restrict__ bb, const float* __restrict__ gg,
        const float* __restrict__ bee, const int* __restrict__ batch,
        float* __restrict__ psum_rep) {
    __shared__ __align__(16) _Float16 As[TB][136];
    __shared__ float sh_pool[NLOC][HID];
    int t = threadIdx.x;
    int w = t >> 6, lane = t & 63;
    int slot4 = lane >> 4, q16 = lane & 15;
    int blk = (int)blockIdx.x;
    int nb = blk * TB;

    for (int i = t; i < NLOC * HID; i += 256) ((float*)sh_pool)[i] = 0.f;
    __syncthreads();

    #pragma unroll 1
    for (int i = 0; i < 4; ++i)
        agg_node_fp8(Hin, dinv, row_start, e_pack,
                     nb + w * 4 + i, slot4, q16, &As[w * 4 + i][0]);

    int quad = lane >> 4, r16 = lane & 15;
    int g0 = batch[nb];
    int gi4[4];
    #pragma unroll
    for (int rr = 0; rr < 4; ++rr) gi4[rr] = batch[nb + quad * 4 + rr];
    __syncthreads();

    half8 a[4];
    #pragma unroll
    for (int kb = 0; kb < 4; ++kb)
        a[kb] = *(const half8*)&As[r16][(kb * 4 + quad) * 8];
    float* rep = psum_rep + (size_t)(blk & (NREP - 1)) * N_GRAPHS * HID;
    const float rs = rsqrtf(1.0f + 1e-5f);
    #pragma unroll
    for (int fi = 0; fi < 2; ++fi) {
        int f = (w * 2 + fi) * 16 + r16;
        const half8* Brow = (const half8*)(Wt + (size_t)f * 128);
        float4v acc = {0.f, 0.f, 0.f, 0.f};
        #pragma unroll
        for (int kb = 0; kb < 4; ++kb)
            acc = __builtin_amdgcn_mfma_f32_16x16x32_f16(a[kb], Brow[kb * 4 + quad],
                                                         acc, 0, 0, 0);
        float b0 = bb[f], gf = gg[f] * rs, e0 = bee[f];
        float partial = 0.f;
        int cur = -1;
        #pragma unroll
        for (int rr = 0; rr < 4; ++rr) {
            float v = fmaf(acc[rr] + b0, gf, e0);
            v = v > 0.f ? v : 0.f;
            int gi = gi4[rr];
            if (gi != cur) {
                if (cur >= 0) {
                    int idx = cur - g0;
                    if (idx < NLOC) atomicAdd(&sh_pool[idx][f], partial);
                    else            atomicAdd(&rep[cur * HID + f], partial);
                }
                partial = 0.f; cur = gi;
            }
            partial += v;
        }
        if (cur >= 0) {
            int idx = cur - g0;
            if (idx < NLOC) atomicAdd(&sh_pool[idx][f], partial);
            else            atomicAdd(&rep[cur * HID + f], partial);
        }
    }
    __syncthreads();
    // flush LDS partials: one replicated global atomic per (graph,f) present
    for (int i = t; i < NLOC * HID; i += 256) {
        int idx = i >> 7, ff = i & 127;
        float v = sh_pool[idx][ff];
        int g = g0 + idx;
        if (v != 0.f && g < N_GRAPHS) atomicAdd(&rep[g * HID + ff], v);
    }
}

// ---------- 9. projection (+ graph counts via binary search, no atomics) ----------

__device__ __forceinline__ int lower_bound_batch(const int* __restrict__ batch, int val) {
    int lo = 0, hi = N_NODES;
    while (lo < hi) {
        int mid = (lo + hi) >> 1;
        if (batch[mid] < val) lo = mid + 1;
        else hi = mid;
    }
    return lo;
}

__global__ void k_final(const float* __restrict__ psum_rep, const int* __restrict__ batch,
                        const float* __restrict__ Wp, const float* __restrict__ bp,
                        float* __restrict__ out) {
    __shared__ float s_p[HID];
    int gi = blockIdx.x, e = threadIdx.x;   // 64 threads
    for (int f = e; f < HID; f += EMB) {
        float v = 0.f;
        #pragma unroll
        for (int r = 0; r < NREP; ++r)
            v += psum_rep[(size_t)r * N_GRAPHS * HID + gi * HID + f];
        s_p[f] = v;
    }
    int lane = e & 63;
    int r = 0;
    if (lane < 2) r = lower_bound_batch(batch, gi + lane);
    int c0 = __shfl(r, 0), c1 = __shfl(r, 1);
    float inv = 1.0f / fmaxf((float)(c1 - c0), 1.0f);
    __syncthreads();
    float acc = bp[e];
    #pragma unroll 8
    for (int f = 0; f < HID; ++f)
        acc = fmaf(s_p[f] * inv, Wp[f * EMB + e], acc);
    out[gi * EMB + e] = acc;
}

// ---------- launcher ----------

extern "C" void kernel_launch(void* const* d_in, const int* in_sizes, int n_in,
                              void* d_out, int out_size, void* d_ws, size_t ws_size,
                              hipStream_t stream) {
    const float* x   = (const float*)d_in[0];
    const int*   src = (const int*)d_in[1];
    const int*   dst = (const int*)d_in[2];
    const int* batch = (const int*)d_in[3];
    const float* W1 = (const float*)d_in[4];
    const float* b1 = (const float*)d_in[5];
    const float* W2 = (const float*)d_in[6];
    const float* b2 = (const float*)d_in[7];
    const float* W3 = (const float*)d_in[8];
    const float* b3 = (const float*)d_in[9];
    const float* g1 = (const float*)d_in[10];
    const float* be1 = (const float*)d_in[11];
    const float* g2 = (const float*)d_in[12];
    const float* be2 = (const float*)d_in[13];
    const float* g3 = (const float*)d_in[14];
    const float* be3 = (const float*)d_in[15];
    const float* Wp = (const float*)d_in[16];
    const float* bp = (const float*)d_in[17];
    float* out = (float*)d_out;

    char* ws = (char*)d_ws;
    size_t o = 0;
    auto alloc = [&](size_t bytes) {
        void* pp = ws + o;
        o += bytes;
        o = (o + 255) & ~255ull;
        return pp;
    };
    int*      cnt       = (int*)alloc(N_NODES * 4);
    int*      row_start = (int*)alloc((N_NODES + 1) * 4);
    int*      csum      = (int*)alloc(NCHUNK * 4);
    float*    dinv      = (float*)alloc(N_NODES * 4);
    unsigned int* e_pack = (unsigned int*)alloc((size_t)(N_EDGES + 16) * 4);
    _Float16* Wt2       = (_Float16*)alloc(HID * HID * 2);
    _Float16* Wt3       = (_Float16*)alloc(HID * HID * 2);
    float*    xp        = (float*)alloc((size_t)N_NODES * 8 * 4);
    unsigned int* H8a   = (unsigned int*)alloc((size_t)N_NODES * HID);  // fp8 rows
    unsigned int* H8b   = (unsigned int*)alloc((size_t)N_NODES * HID);
    float*    psum_rep  = (float*)alloc((size_t)NREP * N_GRAPHS * HID * 4);

    k_init<<<(N_NODES + 255) / 256, 256, 0, stream>>>(cnt);
    k_count<<<(N_EDGES + 255) / 256, 256, 0, stream>>>(dst, cnt, psum_rep,
                                                       W2, W3, Wt2, Wt3, e_pack, x, xp);
    k_chunksum<<<NCHUNK, 256, 0, stream>>>(cnt, csum, dinv);
    k_scan<<<NCHUNK, 256, 0, stream>>>(cnt, csum, row_start);
    k_scatter<<<(N_EDGES + 255) / 256, 256, 0, stream>>>(src, dst, dinv, row_start,
                                                         cnt, e_pack);
    k_agg1<<<N_NODES / TB, 256, 0, stream>>>(xp, dinv, row_start, e_pack,
                                             W1, b1, g1, be1, (unsigned short*)H8a);
    k_fuse2<<<N_NODES / TB, 256, 0, stream>>>(H8a, dinv, row_start, e_pack, Wt2,
                                              b2, g2, be2, (unsigned char*)H8b);
    k_fuse3<<<N_NODES / TB, 256, 0, stream>>>(H8b, dinv, row_start, e_pack, Wt3,
                                              b3, g3, be3, batch, psum_rep);
    k_final<<<N_GRAPHS, EMB, 0, stream>>>(psum_rep, batch, Wp, bp, out);
}

// Round 15
// 243.709 us; speedup vs baseline: 1.1768x; 1.0045x over previous
//
#include <hip/hip_runtime.h>
#include <hip/hip_fp16.h>

#define N_NODES 50000
#define N_EDGES 600000
#define N_GRAPHS 64
#define IN_D 5
#define HID 128
#define EMB 64

#define CHUNK 512
#define NCHUNK ((N_NODES + CHUNK - 1) / CHUNK)   // 98
#define NREP 16          // psum replication factor (contention spread)
#define NLOC 4           // per-block local graph slots (16 sorted nodes span <=2)
#define TB 16            // nodes per fused agg+gemm tile (50000 = 3125*16, no tail)

typedef _Float16 half8 __attribute__((ext_vector_type(8)));
typedef float float4v __attribute__((ext_vector_type(4)));
typedef float floatx2 __attribute__((ext_vector_type(2)));

// e_pack entry: fp16(dinv[src]) in high 16 bits | src (fits 16 bits: 50000<65536)
__device__ __forceinline__ float ep_w(unsigned pe) {
    return (float)__ushort_as_half((unsigned short)(pe >> 16));
}
__device__ __forceinline__ unsigned ep_s(unsigned pe) { return pe & 0xffffu; }

// ---------- 1. init: zero cnt (must complete before k_count) ----------

__global__ __launch_bounds__(256) void k_init(int* __restrict__ cnt) {
    int tid = blockIdx.x * blockDim.x + threadIdx.x;
    if (tid < N_NODES) cnt[tid] = 0;
}

// ---------- 2. degree count + independent prep (xp pad, Wt transpose, psum zero) ----------

__global__ __launch_bounds__(256) void k_count(
        const int* __restrict__ dst, int* __restrict__ cnt,
        float* __restrict__ psum_rep,
        const float* __restrict__ W2, const float* __restrict__ W3,
        _Float16* __restrict__ Wt2, _Float16* __restrict__ Wt3,
        unsigned int* __restrict__ e_pack,
        const float* __restrict__ x, float* __restrict__ xp) {
    int tid = blockIdx.x * blockDim.x + threadIdx.x;
    int nt = gridDim.x * blockDim.x;
    if (tid < N_EDGES) atomicAdd(&cnt[dst[tid]], 1);
    if (tid < 32) e_pack[N_EDGES + tid] = 0u;  // safe pad (quad-chain reads +31)
    for (int i = tid; i < NREP * N_GRAPHS * HID; i += nt) psum_rep[i] = 0.f;
    for (int i = tid; i < N_NODES * 8; i += nt) {
        int f = i & 7, n = i >> 3;
        xp[i] = (f < IN_D) ? x[n * IN_D + f] : 0.f;
    }
    for (int i = tid; i < 2 * HID * HID; i += nt) {
        int rem = i & (HID * HID - 1);
        int k = rem & 127, f = rem >> 7;
        if (i < HID * HID) Wt2[rem] = (_Float16)W2[k * HID + f];
        else               Wt3[rem] = (_Float16)W3[k * HID + f];
    }
}

// ---------- 3. per-chunk sums + dinv ----------

__global__ void k_chunksum(const int* __restrict__ cnt, int* __restrict__ csum,
                           float* __restrict__ dinv) {
    __shared__ int sh[256];
    int b = blockIdx.x, t = threadIdx.x;
    int i0 = b * CHUNK + t, i1 = i0 + 256;
    int v = 0;
    if (i0 < N_NODES) { int c = cnt[i0]; v += c; dinv[i0] = rsqrtf((float)c + 1.0f); }
    if (i1 < N_NODES) { int c = cnt[i1]; v += c; dinv[i1] = rsqrtf((float)c + 1.0f); }
    sh[t] = v; __syncthreads();
    for (int off = 128; off > 0; off >>= 1) {
        if (t < off) sh[t] += sh[t + off];
        __syncthreads();
    }
    if (t == 0) csum[b] = sh[0];
}

// ---------- 4. per-chunk exclusive scan -> row_start ----------

__global__ void k_scan(const int* __restrict__ cnt, const int* __restrict__ csum,
                       int* __restrict__ row_start) {
    __shared__ int ws[4];
    int b = blockIdx.x, t = threadIdx.x;
    int lane = t & 63, w = t >> 6;

    int pre = 0;
    for (int j = lane; j < b; j += 64) pre += csum[j];
    #pragma unroll
    for (int off = 32; off > 0; off >>= 1) pre += __shfl_down(pre, off);
    pre = __shfl(pre, 0);

    int base = b * CHUNK;
    int i0 = base + 2 * t, i1 = i0 + 1;
    int c0 = (i0 < N_NODES) ? cnt[i0] : 0;
    int c1 = (i1 < N_NODES) ? cnt[i1] : 0;
    int v = c0 + c1;
    int s = v;
    #pragma unroll
    for (int off = 1; off < 64; off <<= 1) {
        int u = __shfl_up(s, off);
        if (lane >= off) s += u;
    }
    if (lane == 63) ws[w] = s;
    __syncthreads();
    if (t == 0) {
        int r = 0;
        #pragma unroll
        for (int j = 0; j < 4; ++j) { int xx = ws[j]; ws[j] = r; r += xx; }
    }
    __syncthreads();
    int excl = s - v + ws[w] + pre;
    if (i0 < N_NODES) row_start[i0] = excl;
    if (i1 < N_NODES) row_start[i1] = excl + c0;
    if (b == 0 && t == 0) row_start[N_NODES] = N_EDGES;
}

// ---------- 5. scatter edges into CSR order (4B packed records) ----------

__global__ __launch_bounds__(256) void k_scatter(
        const int* __restrict__ src, const int* __restrict__ dst,
        const float* __restrict__ dinv, const int* __restrict__ row_start,
        int* __restrict__ cnt, unsigned int* __restrict__ e_pack) {
    int e = blockIdx.x * blockDim.x + threadIdx.x;
    if (e >= N_EDGES) return;
    int d = dst[e];
    int pos = row_start[d] + atomicSub(&cnt[d], 1) - 1;
    int s = src[e];
    unsigned hw = (unsigned)__half_as_ushort(__float2half(dinv[s]));
    e_pack[pos] = (hw << 16) | (unsigned)s;
}

// ---------- 6. fused layer 1: quad-chain slot8 agg(xp) + gemm1 + bn + relu -> fp8 ----------
// lane = slot8*8 + q8. Per node: four 8-edge chains in flight (32 edges/iter,
// same structure as the fuse quad-chain win). Mean degree 12 -> ~1 iter/node.
// Tail chains read the 32-entry pad (weight-masked).

__global__ __launch_bounds__(256) void k_agg1(
        const float* __restrict__ xp, const float* __restrict__ dinv,
        const int* __restrict__ row_start, const unsigned int* __restrict__ e_pack,
        const float* __restrict__ W1, const float* __restrict__ b1,
        const float* __restrict__ g1, const float* __restrict__ be1,
        unsigned short* __restrict__ H8u) {
    int t = threadIdx.x;
    int w = t >> 6, lane = t & 63;
    int slot8 = lane >> 3, q8 = lane & 7;
    int nb = blockIdx.x * TB;

    const float rs = rsqrtf(1.0f + 1e-5f);
    int fa = lane * 2, fb = fa + 1;
    float w1a[IN_D], w1b[IN_D];
    #pragma unroll
    for (int k = 0; k < IN_D; ++k) {
        w1a[k] = W1[k * HID + fa];
        w1b[k] = W1[k * HID + fb];
    }
    float b1a = b1[fa], b1b = b1[fb];
    float g1a = g1[fa] * rs, g1b = g1[fb] * rs;
    float e1a = be1[fa], e1b = be1[fb];

    #pragma unroll 1
    for (int i = 0; i < 4; ++i) {
        int n = nb + w * 4 + i;
        int beg = row_start[n], end = row_start[n + 1];
        float acc = 0.f;
        for (int e = beg; e < end; e += 32) {
            unsigned peA = e_pack[e + slot8];
            unsigned peB = e_pack[e + 8 + slot8];
            unsigned peC = e_pack[e + 16 + slot8];
            unsigned peD = e_pack[e + 24 + slot8];   // pad-safe (<= N_EDGES+31)
            float fwA = (e + slot8 < end) ? ep_w(peA) : 0.f;
            float fwB = (e + 8 + slot8 < end) ? ep_w(peB) : 0.f;
            float fwC = (e + 16 + slot8 < end) ? ep_w(peC) : 0.f;
            float fwD = (e + 24 + slot8 < end) ? ep_w(peD) : 0.f;
            float vA = xp[(size_t)ep_s(peA) * 8 + q8];
            float vB = xp[(size_t)ep_s(peB) * 8 + q8];
            float vC = xp[(size_t)ep_s(peC) * 8 + q8];
            float vD = xp[(size_t)ep_s(peD) * 8 + q8];
            acc = fmaf(fwA, vA, acc);
            acc = fmaf(fwB, vB, acc);
            acc = fmaf(fwC, vC, acc);
            acc = fmaf(fwD, vD, acc);
        }
        acc += __shfl_xor(acc, 8);
        acc += __shfl_xor(acc, 16);
        acc += __shfl_xor(acc, 32);
        float di = dinv[n];
        float av = di * fmaf(di, xp[(size_t)n * 8 + q8], acc);
        float a0 = __shfl(av, 0), a1 = __shfl(av, 1), a2 = __shfl(av, 2),
              a3 = __shfl(av, 3), a4 = __shfl(av, 4);
        float va = b1a, vb = b1b;
        va = fmaf(a0, w1a[0], va); vb = fmaf(a0, w1b[0], vb);
        va = fmaf(a1, w1a[1], va); vb = fmaf(a1, w1b[1], vb);
        va = fmaf(a2, w1a[2], va); vb = fmaf(a2, w1b[2], vb);
        va = fmaf(a3, w1a[3], va); vb = fmaf(a3, w1b[3], vb);
        va = fmaf(a4, w1a[4], va); vb = fmaf(a4, w1b[4], vb);
        va = fmaf(va, g1a, e1a);
        vb = fmaf(vb, g1b, e1b);
        va = va > 0.f ? va : 0.f;
        vb = vb > 0.f ? vb : 0.f;
        int p = __builtin_amdgcn_cvt_pk_fp8_f32(va, vb, 0, false);
        H8u[(size_t)n * 64 + lane] = (unsigned short)(p & 0xffff);
    }
}

// ---------- fp8 slot4 agg, quad-chain: 16 edges/iter as four 4-edge chains ----------
// lane = slot4*16 + q16 (uint2/lane, 16 lanes = full 128B row). Four e_pack
// loads issue back-to-back, four gathers together -> 4 independent chains in
// flight, shared acc[8], 2-level reduce. VGPR ~50 < 64 step (no occupancy
// cliff, m69). Tail slots read the pad (weight-masked).

__device__ __forceinline__ void acc8_fp8(float* __restrict__ acc, float fw, uint2 g) {
    floatx2 l0 = __builtin_amdgcn_cvt_pk_f32_fp8(g.x, false);
    floatx2 h0 = __builtin_amdgcn_cvt_pk_f32_fp8(g.x, true);
    floatx2 l1 = __builtin_amdgcn_cvt_pk_f32_fp8(g.y, false);
    floatx2 h1 = __builtin_amdgcn_cvt_pk_f32_fp8(g.y, true);
    acc[0] = fmaf(fw, l0[0], acc[0]);
    acc[1] = fmaf(fw, l0[1], acc[1]);
    acc[2] = fmaf(fw, h0[0], acc[2]);
    acc[3] = fmaf(fw, h0[1], acc[3]);
    acc[4] = fmaf(fw, l1[0], acc[4]);
    acc[5] = fmaf(fw, l1[1], acc[5]);
    acc[6] = fmaf(fw, h1[0], acc[6]);
    acc[7] = fmaf(fw, h1[1], acc[7]);
}

__device__ __forceinline__ void agg_node_fp8(
        const unsigned int* __restrict__ H8, const float* __restrict__ dinv,
        const int* __restrict__ row_start, const unsigned int* __restrict__ e_pack,
        int n, int slot4, int q16, _Float16* __restrict__ asrow) {
    float acc[8];
    #pragma unroll
    for (int j = 0; j < 8; ++j) acc[j] = 0.f;
    int beg = row_start[n], end = row_start[n + 1];
    for (int e = beg; e < end; e += 16) {
        unsigned peA = e_pack[e + slot4];
        unsigned peB = e_pack[e + 4 + slot4];
        unsigned peC = e_pack[e + 8 + slot4];
        unsigned peD = e_pack[e + 12 + slot4];        // pad-safe (<= N_EDGES+15)
        float fwA = (e + slot4 < end) ? ep_w(peA) : 0.f;
        float fwB = (e + 4 + slot4 < end) ? ep_w(peB) : 0.f;
        float fwC = (e + 8 + slot4 < end) ? ep_w(peC) : 0.f;
        float fwD = (e + 12 + slot4 < end) ? ep_w(peD) : 0.f;
        uint2 gA = ((const uint2*)(H8 + (size_t)ep_s(peA) * 32))[q16];
        uint2 gB = ((const uint2*)(H8 + (size_t)ep_s(peB) * 32))[q16];
        uint2 gC = ((const uint2*)(H8 + (size_t)ep_s(peC) * 32))[q16];
        uint2 gD = ((const uint2*)(H8 + (size_t)ep_s(peD) * 32))[q16];
        acc8_fp8(acc, fwA, gA);
        acc8_fp8(acc, fwB, gB);
        acc8_fp8(acc, fwC, gC);
        acc8_fp8(acc, fwD, gD);
    }
    #pragma unroll
    for (int j = 0; j < 8; ++j) {
        float a = acc[j];
        a += __shfl_xor(a, 16);
        a += __shfl_xor(a, 32);
        acc[j] = a;
    }
    if (slot4 == 0) {
        float di = dinv[n];
        uint2 s = ((const uint2*)(H8 + (size_t)n * 32))[q16];
        floatx2 l0 = __builtin_amdgcn_cvt_pk_f32_fp8(s.x, false);
        floatx2 h0 = __builtin_amdgcn_cvt_pk_f32_fp8(s.x, true);
        floatx2 l1 = __builtin_amdgcn_cvt_pk_f32_fp8(s.y, false);
        floatx2 h1 = __builtin_amdgcn_cvt_pk_f32_fp8(s.y, true);
        float sv[8] = {l0[0], l0[1], h0[0], h0[1], l1[0], l1[1], h1[0], h1[1]};
        half8 o;
        #pragma unroll
        for (int j = 0; j < 8; ++j)
            o[j] = (_Float16)(di * fmaf(di, sv[j], acc[j]));
        *(half8*)(asrow + q16 * 8) = o;
    }
}

// ---------- 7. fused layer 2: fp8 agg -> LDS(fp16) -> MFMA + bn + relu -> fp8 ----------

__global__ __launch_bounds__(256) void k_fuse2(
        const unsigned int* __restrict__ Hin, const float* __restrict__ dinv,
        const int* __restrict__ row_start, const unsigned int* __restrict__ e_pack,
        const _Float16* __restrict__ Wt,
        const float* __restrict__ bb, const float* __restrict__ gg,
        const float* __restrict__ bee, unsigned char* __restrict__ out8) {
    __shared__ __align__(16) _Float16 As[TB][136];
    int t = threadIdx.x;
    int w = t >> 6, lane = t & 63;
    int slot4 = lane >> 4, q16 = lane & 15;
    int nb = blockIdx.x * TB;

    #pragma unroll 1
    for (int i = 0; i < 4; ++i)
        agg_node_fp8(Hin, dinv, row_start, e_pack,
                     nb + w * 4 + i, slot4, q16, &As[w * 4 + i][0]);
    __syncthreads();

    int quad = lane >> 4, r16 = lane & 15;
    half8 a[4];
    #pragma unroll
    for (int kb = 0; kb < 4; ++kb)
        a[kb] = *(const half8*)&As[r16][(kb * 4 + quad) * 8];
    const float rs = rsqrtf(1.0f + 1e-5f);
    #pragma unroll
    for (int fi = 0; fi < 2; ++fi) {
        int f = (w * 2 + fi) * 16 + r16;
        const half8* Brow = (const half8*)(Wt + (size_t)f * 128);
        float4v acc = {0.f, 0.f, 0.f, 0.f};
        #pragma unroll
        for (int kb = 0; kb < 4; ++kb)
            acc = __builtin_amdgcn_mfma_f32_16x16x32_f16(a[kb], Brow[kb * 4 + quad],
                                                         acc, 0, 0, 0);
        float b0 = bb[f], gf = gg[f] * rs, e0 = bee[f];
        #pragma unroll
        for (int rr = 0; rr < 4; ++rr) {
            float v = fmaf(acc[rr] + b0, gf, e0);
            v = v > 0.f ? v : 0.f;
            int p = __builtin_amdgcn_cvt_pk_fp8_f32(v, 0.f, 0, false);
            out8[(size_t)(nb + quad * 4 + rr) * 128 + f] = (unsigned char)(p & 0xff);
        }
    }
}

// ---------- 8. fused layer 3: fp8 agg -> MFMA + bn + relu + mean-pool ----------

__global__ __launch_bounds__(256) void k_fuse3(
        const unsigned int* __restrict__ Hin, const float* __restrict__ dinv,
        const int* __restrict__ row_start, const unsigned int* __restrict__ e_pack,
        const _Float16* __restrict__ Wt,
        const float* __restrict__ bb, const float* __restrict__ gg,
        const float* __restrict__ bee, const int* __restrict__ batch,
        float* __restrict__ psum_rep) {
    __shared__ __align__(16) _Float16 As[TB][136];
    __shared__ float sh_pool[NLOC][HID];
    int t = threadIdx.x;
    int w = t >> 6, lane = t & 63;
    int slot4 = lane >> 4, q16 = lane & 15;
    int blk = (int)blockIdx.x;
    int nb = blk * TB;

    for (int i = t; i < NLOC * HID; i += 256) ((float*)sh_pool)[i] = 0.f;
    __syncthreads();

    #pragma unroll 1
    for (int i = 0; i < 4; ++i)
        agg_node_fp8(Hin, dinv, row_start, e_pack,
                     nb + w * 4 + i, slot4, q16, &As[w * 4 + i][0]);

    int quad = lane >> 4, r16 = lane & 15;
    int g0 = batch[nb];
    int gi4[4];
    #pragma unroll
    for (int rr = 0; rr < 4; ++rr) gi4[rr] = batch[nb + quad * 4 + rr];
    __syncthreads();

    half8 a[4];
    #pragma unroll
    for (int kb = 0; kb < 4; ++kb)
        a[kb] = *(const half8*)&As[r16][(kb * 4 + quad) * 8];
    float* rep = psum_rep + (size_t)(blk & (NREP - 1)) * N_GRAPHS * HID;
    const float rs = rsqrtf(1.0f + 1e-5f);
    #pragma unroll
    for (int fi = 0; fi < 2; ++fi) {
        int f = (w * 2 + fi) * 16 + r16;
        const half8* Brow = (const half8*)(Wt + (size_t)f * 128);
        float4v acc = {0.f, 0.f, 0.f, 0.f};
        #pragma unroll
        for (int kb = 0; kb < 4; ++kb)
            acc = __builtin_amdgcn_mfma_f32_16x16x32_f16(a[kb], Brow[kb * 4 + quad],
                                                         acc, 0, 0, 0);
        float b0 = bb[f], gf = gg[f] * rs, e0 = bee[f];
        float partial = 0.f;
        int cur = -1;
        #pragma unroll
        for (int rr = 0; rr < 4; ++rr) {
            float v = fmaf(acc[rr] + b0, gf, e0);
            v = v > 0.f ? v : 0.f;
            int gi = gi4[rr];
            if (gi != cur) {
                if (cur >= 0) {
                    int idx = cur - g0;
                    if (idx < NLOC) atomicAdd(&sh_pool[idx][f], partial);
                    else            atomicAdd(&rep[cur * HID + f], partial);
                }
                partial = 0.f; cur = gi;
            }
            partial += v;
        }
        if (cur >= 0) {
            int idx = cur - g0;
            if (idx < NLOC) atomicAdd(&sh_pool[idx][f], partial);
            else            atomicAdd(&rep[cur * HID + f], partial);
        }
    }
    __syncthreads();
    // flush LDS partials: one replicated global atomic per (graph,f) present
    for (int i = t; i < NLOC * HID; i += 256) {
        int idx = i >> 7, ff = i & 127;
        float v = sh_pool[idx][ff];
        int g = g0 + idx;
        if (v != 0.f && g < N_GRAPHS) atomicAdd(&rep[g * HID + ff], v);
    }
}

// ---------- 9. projection (+ graph counts via binary search, no atomics) ----------

__device__ __forceinline__ int lower_bound_batch(const int* __restrict__ batch, int val) {
    int lo = 0, hi = N_NODES;
    while (lo < hi) {
        int mid = (lo + hi) >> 1;
        if (batch[mid] < val) lo = mid + 1;
        else hi = mid;
    }
    return lo;
}

__global__ void k_final(const float* __restrict__ psum_rep, const int* __restrict__ batch,
                        const float* __restrict__ Wp, const float* __restrict__ bp,
                        float* __restrict__ out) {
    __shared__ float s_p[HID];
    int gi = blockIdx.x, e = threadIdx.x;   // 64 threads
    for (int f = e; f < HID; f += EMB) {
        float v = 0.f;
        #pragma unroll
        for (int r = 0; r < NREP; ++r)
            v += psum_rep[(size_t)r * N_GRAPHS * HID + gi * HID + f];
        s_p[f] = v;
    }
    int lane = e & 63;
    int r = 0;
    if (lane < 2) r = lower_bound_batch(batch, gi + lane);
    int c0 = __shfl(r, 0), c1 = __shfl(r, 1);
    float inv = 1.0f / fmaxf((float)(c1 - c0), 1.0f);
    __syncthreads();
    float acc = bp[e];
    #pragma unroll 8
    for (int f = 0; f < HID; ++f)
        acc = fmaf(s_p[f] * inv, Wp[f * EMB + e], acc);
    out[gi * EMB + e] = acc;
}

// ---------- launcher ----------

extern "C" void kernel_launch(void* const* d_in, const int* in_sizes, int n_in,
                              void* d_out, int out_size, void* d_ws, size_t ws_size,
                              hipStream_t stream) {
    const float* x   = (const float*)d_in[0];
    const int*   src = (const int*)d_in[1];
    const int*   dst = (const int*)d_in[2];
    const int* batch = (const int*)d_in[3];
    const float* W1 = (const float*)d_in[4];
    const float* b1 = (const float*)d_in[5];
    const float* W2 = (const float*)d_in[6];
    const float* b2 = (const float*)d_in[7];
    const float* W3 = (const float*)d_in[8];
    const float* b3 = (const float*)d_in[9];
    const float* g1 = (const float*)d_in[10];
    const float* be1 = (const float*)d_in[11];
    const float* g2 = (const float*)d_in[12];
    const float* be2 = (const float*)d_in[13];
    const float* g3 = (const float*)d_in[14];
    const float* be3 = (const float*)d_in[15];
    const float* Wp = (const float*)d_in[16];
    const float* bp = (const float*)d_in[17];
    float* out = (float*)d_out;

    char* ws = (char*)d_ws;
    size_t o = 0;
    auto alloc = [&](size_t bytes) {
        void* pp = ws + o;
        o += bytes;
        o = (o + 255) & ~255ull;
        return pp;
    };
    int*      cnt       = (int*)alloc(N_NODES * 4);
    int*      row_start = (int*)alloc((N_NODES + 1) * 4);
    int*      csum      = (int*)alloc(NCHUNK * 4);
    float*    dinv      = (float*)alloc(N_NODES * 4);
    unsigned int* e_pack = (unsigned int*)alloc((size_t)(N_EDGES + 32) * 4);
    _Float16* Wt2       = (_Float16*)alloc(HID * HID * 2);
    _Float16* Wt3       = (_Float16*)alloc(HID * HID * 2);
    float*    xp        = (float*)alloc((size_t)N_NODES * 8 * 4);
    unsigned int* H8a   = (unsigned int*)alloc((size_t)N_NODES * HID);  // fp8 rows
    unsigned int* H8b   = (unsigned int*)alloc((size_t)N_NODES * HID);
    float*    psum_rep  = (float*)alloc((size_t)NREP * N_GRAPHS * HID * 4);

    k_init<<<(N_NODES + 255) / 256, 256, 0, stream>>>(cnt);
    k_count<<<(N_EDGES + 255) / 256, 256, 0, stream>>>(dst, cnt, psum_rep,
                                                       W2, W3, Wt2, Wt3, e_pack, x, xp);
    k_chunksum<<<NCHUNK, 256, 0, stream>>>(cnt, csum, dinv);
    k_scan<<<NCHUNK, 256, 0, stream>>>(cnt, csum, row_start);
    k_scatter<<<(N_EDGES + 255) / 256, 256, 0, stream>>>(src, dst, dinv, row_start,
                                                         cnt, e_pack);
    k_agg1<<<N_NODES / TB, 256, 0, stream>>>(xp, dinv, row_start, e_pack,
                                             W1, b1, g1, be1, (unsigned short*)H8a);
    k_fuse2<<<N_NODES / TB, 256, 0, stream>>>(H8a, dinv, row_start, e_pack, Wt2,
                                              b2, g2, be2, (unsigned char*)H8b);
    k_fuse3<<<N_NODES / TB, 256, 0, stream>>>(H8b, dinv, row_start, e_pack, Wt3,
                                              b3, g3, be3, batch, psum_rep);
    k_final<<<N_GRAPHS, EMB, 0, stream>>>(psum_rep, batch, Wp, bp, out);
}